// Round 6
// baseline (832.906 us; speedup 1.0000x reference)
//
#include <hip/hip_runtime.h>
#include <math.h>

#define SEQ   2048
#define HID   1024
#define NH    16
#define HD    64
#define NKH   204          // heavy hitters = int(2048*0.1)
#define LCOMP 512          // compressed length = 2048/4
#define NCAT  716          // 204 + 512
#define NCATP 768          // padded to multiple of 64 (52 pad keys)
#define SCALE 0.125f       // 1/sqrt(64)
#define NSLAB (NH * (SEQ/16))   // 2048 influence partial slabs

typedef __attribute__((ext_vector_type(8))) short short8;   // 8 bf16 (4 VGPRs)
typedef __attribute__((ext_vector_type(4))) float f32x4;    // MFMA accumulator

// ---- bf16 split helpers (RNE) -------------------------------------------
__device__ __forceinline__ short f2bf(float f) {
    unsigned u = __builtin_bit_cast(unsigned, f);
    u += 0x7FFFu + ((u >> 16) & 1u);
    return (short)(u >> 16);
}
__device__ __forceinline__ float bf2f(short h) {
    unsigned u = ((unsigned)(unsigned short)h) << 16;
    return __builtin_bit_cast(float, u);
}

// ---------------------------------------------------------------------------
// One-pass splitters: f32 -> bf16 hi/lo.
// ---------------------------------------------------------------------------
__global__ __launch_bounds__(256) void splitx_k(const float* __restrict__ X,
                                                unsigned short* __restrict__ hi,
                                                unsigned short* __restrict__ lo) {
    size_t g = ((size_t)blockIdx.x * 256 + threadIdx.x) * 4;
    float4 v4 = *(const float4*)(X + g);
    ushort4 h4, l4;
    short hb;
    hb = f2bf(v4.x); h4.x = hb; l4.x = (unsigned short)f2bf(v4.x - bf2f(hb));
    hb = f2bf(v4.y); h4.y = hb; l4.y = (unsigned short)f2bf(v4.y - bf2f(hb));
    hb = f2bf(v4.z); h4.z = hb; l4.z = (unsigned short)f2bf(v4.z - bf2f(hb));
    hb = f2bf(v4.w); h4.w = hb; l4.w = (unsigned short)f2bf(v4.w - bf2f(hb));
    *(ushort4*)(hi + g) = h4;
    *(ushort4*)(lo + g) = l4;
}

__global__ __launch_bounds__(256) void splitw_k(const float* __restrict__ W,
                                                unsigned short* __restrict__ hi,
                                                unsigned short* __restrict__ lo) {
    __shared__ float tile[64][65];
    int n0 = blockIdx.x * 64, k0 = blockIdx.y * 64;
    int t = threadIdx.x;
    int r = t >> 4, c4 = (t & 15) * 4;
    #pragma unroll
    for (int i = 0; i < 4; ++i) {
        float4 v4 = *(const float4*)(W + (size_t)(k0 + i*16 + r) * HID + n0 + c4);
        tile[i*16 + r][c4+0] = v4.x; tile[i*16 + r][c4+1] = v4.y;
        tile[i*16 + r][c4+2] = v4.z; tile[i*16 + r][c4+3] = v4.w;
    }
    __syncthreads();
    #pragma unroll
    for (int i = 0; i < 4; ++i) {
        int n = i*16 + r;
        float v0 = tile[c4+0][n], v1 = tile[c4+1][n];
        float v2 = tile[c4+2][n], v3 = tile[c4+3][n];
        ushort4 h4, l4;
        short hb;
        hb = f2bf(v0); h4.x = hb; l4.x = (unsigned short)f2bf(v0 - bf2f(hb));
        hb = f2bf(v1); h4.y = hb; l4.y = (unsigned short)f2bf(v1 - bf2f(hb));
        hb = f2bf(v2); h4.z = hb; l4.z = (unsigned short)f2bf(v2 - bf2f(hb));
        hb = f2bf(v3); h4.w = hb; l4.w = (unsigned short)f2bf(v3 - bf2f(hb));
        size_t o = (size_t)(n0 + n) * HID + k0 + c4;
        *(ushort4*)(hi + o) = h4;
        *(ushort4*)(lo + o) = l4;
    }
}

// ---------------------------------------------------------------------------
// bf16x3 MFMA GEMM v2: grid (64,16), wave = 32m x 16n.  3 indep chains per
// m-tile (hh/lh/hl), 1-deep kc prefetch.  4 blocks/CU -> 16 waves/CU.
// ---------------------------------------------------------------------------
__global__ __launch_bounds__(256) void gemm_sp(const unsigned short* __restrict__ Ahi,
                                               const unsigned short* __restrict__ Alo,
                                               const unsigned short* __restrict__ Bthi,
                                               const unsigned short* __restrict__ Btlo,
                                               float* __restrict__ Cf,
                                               unsigned short* __restrict__ Hhi,
                                               unsigned short* __restrict__ Hlo) {
    int t = threadIdx.x, lane = t & 63, w = t >> 6;
    int quad = lane >> 4, c16 = lane & 15;
    int m0 = blockIdx.x * 32;
    int nw = blockIdx.y * 64 + w * 16;
    const unsigned short* a0h = Ahi + (size_t)(m0 + c16) * HID;
    const unsigned short* a0l = Alo + (size_t)(m0 + c16) * HID;
    const unsigned short* b0h = Bthi + (size_t)(nw + c16) * HID;
    const unsigned short* b0l = Btlo + (size_t)(nw + c16) * HID;
    f32x4 ahh[2], alh[2], ahl[2];
    #pragma unroll
    for (int mt = 0; mt < 2; ++mt) {
        ahh[mt] = (f32x4){0.f,0.f,0.f,0.f};
        alh[mt] = (f32x4){0.f,0.f,0.f,0.f};
        ahl[mt] = (f32x4){0.f,0.f,0.f,0.f};
    }
    short8 cA0h, cA0l, cA1h, cA1l, cBh, cBl;
    {
        int ko = quad * 8;
        cA0h = *(const short8*)(a0h + ko);
        cA0l = *(const short8*)(a0l + ko);
        cA1h = *(const short8*)(a0h + 16*HID + ko);
        cA1l = *(const short8*)(a0l + 16*HID + ko);
        cBh  = *(const short8*)(b0h + ko);
        cBl  = *(const short8*)(b0l + ko);
    }
    #pragma unroll
    for (int kc = 0; kc < 32; ++kc) {
        short8 nA0h, nA0l, nA1h, nA1l, nBh, nBl;
        if (kc < 31) {
            int ko = (kc+1)*32 + quad*8;
            nA0h = *(const short8*)(a0h + ko);
            nA0l = *(const short8*)(a0l + ko);
            nA1h = *(const short8*)(a0h + 16*HID + ko);
            nA1l = *(const short8*)(a0l + 16*HID + ko);
            nBh  = *(const short8*)(b0h + ko);
            nBl  = *(const short8*)(b0l + ko);
        }
        ahh[0] = __builtin_amdgcn_mfma_f32_16x16x32_bf16(cA0h, cBh, ahh[0], 0, 0, 0);
        ahh[1] = __builtin_amdgcn_mfma_f32_16x16x32_bf16(cA1h, cBh, ahh[1], 0, 0, 0);
        alh[0] = __builtin_amdgcn_mfma_f32_16x16x32_bf16(cA0l, cBh, alh[0], 0, 0, 0);
        alh[1] = __builtin_amdgcn_mfma_f32_16x16x32_bf16(cA1l, cBh, alh[1], 0, 0, 0);
        ahl[0] = __builtin_amdgcn_mfma_f32_16x16x32_bf16(cA0h, cBl, ahl[0], 0, 0, 0);
        ahl[1] = __builtin_amdgcn_mfma_f32_16x16x32_bf16(cA1h, cBl, ahl[1], 0, 0, 0);
        if (kc < 31) {
            cA0h = nA0h; cA0l = nA0l; cA1h = nA1h; cA1l = nA1l;
            cBh = nBh; cBl = nBl;
        }
    }
    #pragma unroll
    for (int mt = 0; mt < 2; ++mt)
    #pragma unroll
    for (int i = 0; i < 4; ++i) {
        int m = m0 + mt*16 + quad*4 + i;
        int n = nw + c16;
        float val = ahh[mt][i] + alh[mt][i] + ahl[mt][i];
        if (Cf) Cf[(size_t)m * HID + n] = val;
        if (Hhi) {
            int hh_ = n >> 6, d = n & 63;
            size_t o = ((size_t)hh_ * SEQ + m) * HD + d;
            short hb = f2bf(val);
            Hhi[o] = (unsigned short)hb;
            Hlo[o] = (unsigned short)f2bf(val - bf2f(hb));
        }
    }
}

// ---------------------------------------------------------------------------
// Score stats v3: 3 indep MFMA chains/tile + 1-deep B prefetch; influence
// written as plain coalesced per-block column-sum strips (no atomics).
// Block = (head, 16 q rows), wave w owns keys [w*512, +512).
// ---------------------------------------------------------------------------
__global__ __launch_bounds__(256) void score_mfma(const unsigned short* __restrict__ qhi,
                                                  const unsigned short* __restrict__ qlo,
                                                  const unsigned short* __restrict__ khi,
                                                  const unsigned short* __restrict__ klo,
                                                  float* __restrict__ ent,
                                                  float* __restrict__ mxa,
                                                  float* __restrict__ part) {
    __shared__ float redm[4][16], redl[4][16], rede[4][16];
    int h  = blockIdx.x;
    int qb = blockIdx.y;
    int m0 = qb * 16;
    int t  = threadIdx.x;
    int lane = t & 63, w = t >> 6;
    int quad = lane >> 4, c16 = lane & 15;

    const unsigned short* qph = qhi + ((size_t)h * SEQ + m0 + c16) * HD;
    const unsigned short* qpl = qlo + ((size_t)h * SEQ + m0 + c16) * HD;
    short8 Ah0 = *(const short8*)(qph + quad*8);
    short8 Ah1 = *(const short8*)(qph + 32 + quad*8);
    short8 Al0 = *(const short8*)(qpl + quad*8);
    short8 Al1 = *(const short8*)(qpl + 32 + quad*8);

    float sreg[32][4];
    short8 cb0, cb1, cb2, cb3;
    {
        int key = (w * 32) * 16 + c16;
        const unsigned short* kbh = khi + ((size_t)h * SEQ + key) * HD + quad*8;
        const unsigned short* kbl = klo + ((size_t)h * SEQ + key) * HD + quad*8;
        cb0 = *(const short8*)kbh;
        cb1 = *(const short8*)(kbh + 32);
        cb2 = *(const short8*)kbl;
        cb3 = *(const short8*)(kbl + 32);
    }
    #pragma unroll
    for (int nt = 0; nt < 32; ++nt) {
        short8 nb0, nb1, nb2, nb3;
        if (nt < 31) {
            int key = (w * 32 + nt + 1) * 16 + c16;
            const unsigned short* kbh = khi + ((size_t)h * SEQ + key) * HD + quad*8;
            const unsigned short* kbl = klo + ((size_t)h * SEQ + key) * HD + quad*8;
            nb0 = *(const short8*)kbh;
            nb1 = *(const short8*)(kbh + 32);
            nb2 = *(const short8*)kbl;
            nb3 = *(const short8*)(kbl + 32);
        }
        f32x4 ahh = {0.f,0.f,0.f,0.f}, alh = {0.f,0.f,0.f,0.f}, ahl = {0.f,0.f,0.f,0.f};
        ahh = __builtin_amdgcn_mfma_f32_16x16x32_bf16(Ah0, cb0, ahh, 0, 0, 0);
        alh = __builtin_amdgcn_mfma_f32_16x16x32_bf16(Al0, cb0, alh, 0, 0, 0);
        ahl = __builtin_amdgcn_mfma_f32_16x16x32_bf16(Ah0, cb2, ahl, 0, 0, 0);
        ahh = __builtin_amdgcn_mfma_f32_16x16x32_bf16(Ah1, cb1, ahh, 0, 0, 0);
        alh = __builtin_amdgcn_mfma_f32_16x16x32_bf16(Al1, cb1, alh, 0, 0, 0);
        ahl = __builtin_amdgcn_mfma_f32_16x16x32_bf16(Ah1, cb3, ahl, 0, 0, 0);
        #pragma unroll
        for (int i = 0; i < 4; ++i)
            sreg[nt][i] = (ahh[i] + alh[i] + ahl[i]) * SCALE;
        if (nt < 31) { cb0 = nb0; cb1 = nb1; cb2 = nb2; cb3 = nb3; }
    }

    // ---- global row max ----
    float m[4];
    #pragma unroll
    for (int i = 0; i < 4; ++i) {
        float mm = -1e30f;
        #pragma unroll
        for (int nt = 0; nt < 32; ++nt) mm = fmaxf(mm, sreg[nt][i]);
        #pragma unroll
        for (int off = 1; off <= 8; off <<= 1) mm = fmaxf(mm, __shfl_xor(mm, off));
        m[i] = mm;
    }
    if (c16 == 0) {
        #pragma unroll
        for (int i = 0; i < 4; ++i) redm[w][quad*4 + i] = m[i];
    }
    __syncthreads();
    #pragma unroll
    for (int i = 0; i < 4; ++i) {
        int row = quad*4 + i;
        m[i] = fmaxf(fmaxf(redm[0][row], redm[1][row]),
                     fmaxf(redm[2][row], redm[3][row]));
    }

    // ---- single exp pass: l = sum(t), ee = sum(t*d); sreg <- t ----
    float l[4], ee[4];
    #pragma unroll
    for (int i = 0; i < 4; ++i) {
        float ll = 0.f, e2 = 0.f;
        #pragma unroll
        for (int nt = 0; nt < 32; ++nt) {
            float d = sreg[nt][i] - m[i];
            float tt = expf(d);
            sreg[nt][i] = tt;
            ll += tt;
            e2 += tt * d;
        }
        #pragma unroll
        for (int off = 1; off <= 8; off <<= 1) {
            ll += __shfl_xor(ll, off);
            e2 += __shfl_xor(e2, off);
        }
        l[i] = ll; ee[i] = e2;
    }
    if (c16 == 0) {
        #pragma unroll
        for (int i = 0; i < 4; ++i) { redl[w][quad*4 + i] = l[i]; rede[w][quad*4 + i] = ee[i]; }
    }
    __syncthreads();
    float inv[4];
    #pragma unroll
    for (int i = 0; i < 4; ++i) {
        int row = quad*4 + i;
        l[i]  = redl[0][row] + redl[1][row] + redl[2][row] + redl[3][row];
        ee[i] = rede[0][row] + rede[1][row] + rede[2][row] + rede[3][row];
        inv[i] = 1.f / l[i];
    }
    if (w == 0 && c16 == 0) {
        #pragma unroll
        for (int i = 0; i < 4; ++i) {
            mxa[h*SEQ + m0 + quad*4 + i] = inv[i];
            ent[h*SEQ + m0 + quad*4 + i] = logf(l[i]) - ee[i] * inv[i];
        }
    }

    // ---- influence partials: plain coalesced stores, no atomics ----
    float* pslab = part + (size_t)(h * (SEQ/16) + qb) * SEQ;
    #pragma unroll
    for (int nt = 0; nt < 32; ++nt) {
        float cs = sreg[nt][0]*inv[0] + sreg[nt][1]*inv[1]
                 + sreg[nt][2]*inv[2] + sreg[nt][3]*inv[3];
        cs += __shfl_xor(cs, 16);
        cs += __shfl_xor(cs, 32);
        if (lane < 16) pslab[(w*32 + nt)*16 + lane] = cs;
    }
}

// stage-1 influence reduction: red[g][s] = sum of 32 slabs
__global__ __launch_bounds__(256) void reduce_infl(const float* __restrict__ part,
                                                   float* __restrict__ red) {
    int s = blockIdx.x * 256 + threadIdx.x;
    int g = blockIdx.y;
    const float* p = part + (size_t)g * 32 * SEQ + s;
    float a = 0.f;
    #pragma unroll 8
    for (int i = 0; i < 32; ++i) a += p[(size_t)i * SEQ];
    red[(size_t)g * SEQ + s] = a;
}

__global__ __launch_bounds__(256) void importance_k(const float* __restrict__ ent,
                                                    const float* __restrict__ mxa,
                                                    const float* __restrict__ red,
                                                    float* __restrict__ imp) {
    int s = blockIdx.x * 256 + threadIdx.x;
    float es = 0.f, ms = 0.f;
    #pragma unroll
    for (int h = 0; h < NH; ++h) { es += ent[h*SEQ + s]; ms += mxa[h*SEQ + s]; }
    float inf = 0.f;
    #pragma unroll 8
    for (int g = 0; g < 64; ++g) inf += red[(size_t)g * SEQ + s];
    imp[s] = (-0.4f*es + 0.3f*ms + 0.3f*inf) * (1.f/16.f);
}

// Deterministic top-k by rank counting (matches lax.top_k set semantics).
__global__ __launch_bounds__(256) void topk_k(const float* __restrict__ imp,
                                              int* __restrict__ hh) {
    __shared__ float si[SEQ];
    int t = threadIdx.x, s = blockIdx.x * 256 + t;
    for (int i = t; i < SEQ; i += 256) si[i] = imp[i];
    __syncthreads();
    float v = si[s];
    int rank = 0;
    #pragma unroll 1
    for (int i = 0; i < SEQ; ++i) {
        float u = si[i];
        rank += (u > v) || (u == v && i < s);
    }
    if (rank < NKH) hh[rank] = s;
}

// per-(h,s) L2 norm of a 64-dim head vector (one wave each)
__global__ __launch_bounds__(256) void norms_k(const float* __restrict__ x,
                                               float* __restrict__ n) {
    int t = threadIdx.x;
    int wid = blockIdx.x * 4 + (t >> 6);
    int lane = t & 63;
    int h = wid >> 11, s = wid & 2047;
    float v = x[(size_t)s * HID + h * HD + lane];
    float ss = v * v;
    #pragma unroll
    for (int off = 32; off; off >>= 1) ss += __shfl_xor(ss, off);
    if (lane == 0) n[h*SEQ + s] = sqrtf(ss);
}

// in-place softmax over SEQ per head (one block per head)
__global__ __launch_bounds__(256) void softw_k(float* __restrict__ n) {
    __shared__ float red[8];
    int h = blockIdx.x, t = threadIdx.x, lane = t & 63, w = t >> 6;
    float* nh = n + (size_t)h * SEQ;
    float m = -1e30f;
    for (int i = t; i < SEQ; i += 256) m = fmaxf(m, nh[i]);
    #pragma unroll
    for (int off = 32; off; off >>= 1) m = fmaxf(m, __shfl_xor(m, off));
    if (lane == 0) red[w] = m;
    __syncthreads();
    m = fmaxf(fmaxf(red[0], red[1]), fmaxf(red[2], red[3]));
    float z = 0.f;
    for (int i = t; i < SEQ; i += 256) z += expf(nh[i] - m);
    #pragma unroll
    for (int off = 32; off; off >>= 1) z += __shfl_xor(z, off);
    if (lane == 0) red[4 + w] = z;
    __syncthreads();
    z = red[4] + red[5] + red[6] + red[7];
    for (int i = t; i < SEQ; i += 256) nh[i] = expf(nh[i] - m) / z;
}

// group-4 weighted pooling of K -> pre-split bf16 [h][key][d]
__global__ __launch_bounds__(256) void poolk_k(const float* __restrict__ src,
                                               const float* __restrict__ w,
                                               unsigned short* __restrict__ hi,
                                               unsigned short* __restrict__ lo) {
    int g = blockIdx.x * 256 + threadIdx.x;
    int d = g & 63, rest = g >> 6;
    int l = rest & 511, h = rest >> 9;
    const float* wp = w + (size_t)h * SEQ + l * 4;
    float w0 = wp[0], w1 = wp[1], w2 = wp[2], w3 = wp[3];
    float wsum = w0 + w1 + w2 + w3 + 1e-8f;
    size_t base = (size_t)(l*4) * HID + h * HD + d;
    float val = (src[base]*w0 + src[base+HID]*w1 + src[base+2*HID]*w2 + src[base+3*HID]*w3) / wsum;
    size_t dst = ((size_t)h * NCATP + NKH + l) * HD + d;
    short hb = f2bf(val);
    hi[dst] = (unsigned short)hb;
    lo[dst] = (unsigned short)f2bf(val - bf2f(hb));
}

// group-4 weighted pooling of V -> pre-split bf16 TRANSPOSED [h][d][key]
__global__ __launch_bounds__(256) void poolv_k(const float* __restrict__ src,
                                               const float* __restrict__ w,
                                               unsigned short* __restrict__ hi,
                                               unsigned short* __restrict__ lo) {
    int g = blockIdx.x * 256 + threadIdx.x;
    int d = g & 63, rest = g >> 6;
    int l = rest & 511, h = rest >> 9;
    const float* wp = w + (size_t)h * SEQ + l * 4;
    float w0 = wp[0], w1 = wp[1], w2 = wp[2], w3 = wp[3];
    float wsum = w0 + w1 + w2 + w3 + 1e-8f;
    size_t base = (size_t)(l*4) * HID + h * HD + d;
    float val = (src[base]*w0 + src[base+HID]*w1 + src[base+2*HID]*w2 + src[base+3*HID]*w3) / wsum;
    size_t dst = ((size_t)h * HD + d) * NCATP + NKH + l;
    short hb = f2bf(val);
    hi[dst] = (unsigned short)hb;
    lo[dst] = (unsigned short)f2bf(val - bf2f(hb));
}

// gather heavy-hitter k/v rows -> pre-split bf16 (K direct, V transposed)
__global__ __launch_bounds__(256) void gather_k(const float* __restrict__ k,
                                                const float* __restrict__ v,
                                                const int* __restrict__ hh,
                                                unsigned short* __restrict__ khi,
                                                unsigned short* __restrict__ klo,
                                                unsigned short* __restrict__ vthi,
                                                unsigned short* __restrict__ vtlo) {
    int g = blockIdx.x * 256 + threadIdx.x;
    int d = g & 63, rest = g >> 6;
    int i = rest % NKH, h = rest / NKH;
    int s = hh[i];
    float kv = k[(size_t)s * HID + h * HD + d];
    float vv = v[(size_t)s * HID + h * HD + d];
    size_t kd = ((size_t)h * NCATP + i) * HD + d;
    size_t vd = ((size_t)h * HD + d) * NCATP + i;
    short hb = f2bf(kv);
    khi[kd] = (unsigned short)hb;
    klo[kd] = (unsigned short)f2bf(kv - bf2f(hb));
    hb = f2bf(vv);
    vthi[vd] = (unsigned short)hb;
    vtlo[vd] = (unsigned short)f2bf(vv - bf2f(hb));
}

// zero the 52 pad keys per head in all four split arrays
__global__ __launch_bounds__(256) void padzero_k(unsigned short* __restrict__ khi,
                                                 unsigned short* __restrict__ klo,
                                                 unsigned short* __restrict__ vthi,
                                                 unsigned short* __restrict__ vtlo) {
    int g = blockIdx.x * 256 + threadIdx.x;
    if (g >= NH * (NCATP - NCAT) * HD) return;
    int d = g & 63, rest = g >> 6;
    int i = rest % (NCATP - NCAT), h = rest / (NCATP - NCAT);
    size_t kd = ((size_t)h * NCATP + NCAT + i) * HD + d;
    size_t vd = ((size_t)h * HD + d) * NCATP + NCAT + i;
    khi[kd] = 0; klo[kd] = 0;
    vthi[vd] = 0; vtlo[vd] = 0;
}

// ---------------------------------------------------------------------------
// Final attention via bf16x3 MFMA (3-chain).  Q pre-split; emits pre-split ao.
// ---------------------------------------------------------------------------
__global__ __launch_bounds__(256) void attn_mfma(const unsigned short* __restrict__ qhi,
                                                 const unsigned short* __restrict__ qlo,
                                                 const unsigned short* __restrict__ kchi,
                                                 const unsigned short* __restrict__ kclo,
                                                 const unsigned short* __restrict__ vthi,
                                                 const unsigned short* __restrict__ vtlo,
                                                 unsigned short* __restrict__ aohi,
                                                 unsigned short* __restrict__ aolo) {
    __shared__ unsigned short phi[16][776];   // 24.8 KB
    __shared__ unsigned short plo[16][776];   // 24.8 KB
    __shared__ float redm[4][16], redl[4][16];
    int h  = blockIdx.x;
    int m0 = blockIdx.y * 16;
    int t  = threadIdx.x;
    int lane = t & 63, w = t >> 6;
    int quad = lane >> 4, c16 = lane & 15;

    const unsigned short* qph = qhi + ((size_t)h * SEQ + m0 + c16) * HD;
    const unsigned short* qpl = qlo + ((size_t)h * SEQ + m0 + c16) * HD;
    short8 Ah0 = *(const short8*)(qph + quad*8);
    short8 Ah1 = *(const short8*)(qph + 32 + quad*8);
    short8 Al0 = *(const short8*)(qpl + quad*8);
    short8 Al1 = *(const short8*)(qpl + 32 + quad*8);

    // ---- QK^T: 12 tiles of 16 keys, 3 indep chains ----
    float sreg[12][4];
    #pragma unroll
    for (int nt = 0; nt < 12; ++nt) {
        int key = w*192 + nt*16 + c16;
        const unsigned short* kbh = kchi + ((size_t)h * NCATP + key) * HD + quad*8;
        const unsigned short* kbl = kclo + ((size_t)h * NCATP + key) * HD + quad*8;
        short8 Bh0 = *(const short8*)kbh;
        short8 Bh1 = *(const short8*)(kbh + 32);
        short8 Bl0 = *(const short8*)kbl;
        short8 Bl1 = *(const short8*)(kbl + 32);
        f32x4 ahh = {0.f,0.f,0.f,0.f}, alh = {0.f,0.f,0.f,0.f}, ahl = {0.f,0.f,0.f,0.f};
        ahh = __builtin_amdgcn_mfma_f32_16x16x32_bf16(Ah0, Bh0, ahh, 0, 0, 0);
        alh = __builtin_amdgcn_mfma_f32_16x16x32_bf16(Al0, Bh0, alh, 0, 0, 0);
        ahl = __builtin_amdgcn_mfma_f32_16x16x32_bf16(Ah0, Bl0, ahl, 0, 0, 0);
        ahh = __builtin_amdgcn_mfma_f32_16x16x32_bf16(Ah1, Bh1, ahh, 0, 0, 0);
        alh = __builtin_amdgcn_mfma_f32_16x16x32_bf16(Al1, Bh1, alh, 0, 0, 0);
        ahl = __builtin_amdgcn_mfma_f32_16x16x32_bf16(Ah1, Bl1, ahl, 0, 0, 0);
        bool bad = key >= NCAT;
        #pragma unroll
        for (int i = 0; i < 4; ++i)
            sreg[nt][i] = bad ? -1e30f : (ahh[i] + alh[i] + ahl[i]) * SCALE;
    }

    // ---- softmax ----
    float m[4], l[4];
    #pragma unroll
    for (int i = 0; i < 4; ++i) {
        float mm = -1e30f;
        #pragma unroll
        for (int nt = 0; nt < 12; ++nt) mm = fmaxf(mm, sreg[nt][i]);
        #pragma unroll
        for (int off = 1; off <= 8; off <<= 1) mm = fmaxf(mm, __shfl_xor(mm, off));
        m[i] = mm;
    }
    if (c16 == 0) {
        #pragma unroll
        for (int i = 0; i < 4; ++i) redm[w][quad*4 + i] = m[i];
    }
    __syncthreads();
    #pragma unroll
    for (int i = 0; i < 4; ++i) {
        int row = quad*4 + i;
        m[i] = fmaxf(fmaxf(redm[0][row], redm[1][row]),
                     fmaxf(redm[2][row], redm[3][row]));
    }
    #pragma unroll
    for (int i = 0; i < 4; ++i) {
        float ll = 0.f;
        #pragma unroll
        for (int nt = 0; nt < 12; ++nt) ll += expf(sreg[nt][i] - m[i]);
        #pragma unroll
        for (int off = 1; off <= 8; off <<= 1) ll += __shfl_xor(ll, off);
        l[i] = ll;
    }
    if (c16 == 0) {
        #pragma unroll
        for (int i = 0; i < 4; ++i) redl[w][quad*4 + i] = l[i];
    }
    __syncthreads();
    float inv[4];
    #pragma unroll
    for (int i = 0; i < 4; ++i) {
        int row = quad*4 + i;
        inv[i] = 1.f / (redl[0][row] + redl[1][row] + redl[2][row] + redl[3][row]);
    }

    // ---- probs -> LDS, pre-split bf16 ----
    #pragma unroll
    for (int nt = 0; nt < 12; ++nt) {
        int key = w*192 + nt*16 + c16;
        #pragma unroll
        for (int i = 0; i < 4; ++i) {
            float p = expf(sreg[nt][i] - m[i]) * inv[i];
            short ph = f2bf(p);
            phi[quad*4 + i][key] = (unsigned short)ph;
            plo[quad*4 + i][key] = (unsigned short)f2bf(p - bf2f(ph));
        }
    }
    __syncthreads();

    // ---- PV: wave w computes dims [w*16, w*16+16), 3 indep chains ----
    int dim = w*16 + c16;
    const unsigned short* vh = vthi + ((size_t)h * HD + dim) * NCATP;
    const unsigned short* vl = vtlo + ((size_t)h * HD + dim) * NCATP;
    f32x4 ohh = {0.f,0.f,0.f,0.f}, olh = {0.f,0.f,0.f,0.f}, ohl = {0.f,0.f,0.f,0.f};
    #pragma unroll 4
    for (int s = 0; s < 24; ++s) {
        int k0 = s*32 + quad*8;
        short8 Ph = *(const short8*)&phi[c16][k0];
        short8 Pl = *(const short8*)&plo[c16][k0];
        short8 Vh = *(const short8*)(vh + k0);
        short8 Vl = *(const short8*)(vl + k0);
        ohh = __builtin_amdgcn_mfma_f32_16x16x32_bf16(Ph, Vh, ohh, 0, 0, 0);
        olh = __builtin_amdgcn_mfma_f32_16x16x32_bf16(Pl, Vh, olh, 0, 0, 0);
        ohl = __builtin_amdgcn_mfma_f32_16x16x32_bf16(Ph, Vl, ohl, 0, 0, 0);
    }
    #pragma unroll
    for (int i = 0; i < 4; ++i) {
        float val = ohh[i] + olh[i] + ohl[i];
        size_t o = (size_t)(m0 + quad*4 + i) * HID + h * HD + dim;
        short hb = f2bf(val);
        aohi[o] = (unsigned short)hb;
        aolo[o] = (unsigned short)f2bf(val - bf2f(hb));
    }
}

// ---------------------------------------------------------------------------
extern "C" void kernel_launch(void* const* d_in, const int* in_sizes, int n_in,
                              void* d_out, int out_size, void* d_ws, size_t ws_size,
                              hipStream_t stream) {
    const float* x  = (const float*)d_in[0];
    const float* Wq = (const float*)d_in[1];
    const float* Wk = (const float*)d_in[2];
    const float* Wv = (const float*)d_in[3];
    const float* Wo = (const float*)d_in[4];
    float* out = (float*)d_out;

    char* base = (char*)d_ws;                       // ~72.5 MB total
    const size_t MB = 1u << 20;
    float* kf = (float*)(base + 0);                 // 8 MB
    float* vf = (float*)(base + 8*MB);              // 8 MB
    unsigned short* xhi = (unsigned short*)(base + 16*MB);   // 4 MB
    unsigned short* xlo = (unsigned short*)(base + 20*MB);   // 4 MB
    unsigned short* w1hi = (unsigned short*)(base + 24*MB);  // 2 MB (Wq, later Wo)
    unsigned short* w1lo = (unsigned short*)(base + 26*MB);
    unsigned short* w2hi = (unsigned short*)(base + 28*MB);  // Wk
    unsigned short* w2lo = (unsigned short*)(base + 30*MB);
    unsigned short* w3hi = (unsigned short*)(base + 32*MB);  // Wv
    unsigned short* w3lo = (unsigned short*)(base + 34*MB);
    unsigned short* qsphi = (unsigned short*)(base + 36*MB); // 4 MB [h][s][d]
    unsigned short* qsplo = (unsigned short*)(base + 40*MB);
    unsigned short* ksphi = (unsigned short*)(base + 44*MB); // 4 MB [h][s][d]
    unsigned short* ksplo = (unsigned short*)(base + 48*MB);
    // aliases (ordered reuse, safe on an in-order stream):
    unsigned short* aohi = xhi;                     // after QKV gemms read xsp
    unsigned short* aolo = xlo;
    const size_t CATB = (size_t)NH * NCATP * HD * 2; // 1.5 MB
    unsigned short* kchi = (unsigned short*)(base + 44*MB);          // after score_mfma
    unsigned short* kclo = (unsigned short*)(base + 44*MB + CATB);
    unsigned short* vthi = (unsigned short*)(base + 44*MB + 2*CATB);
    unsigned short* vtlo = (unsigned short*)(base + 44*MB + 3*CATB);
    // small buffers
    char* sm = base + 52*MB;
    float* ent  = (float*)sm;                 sm += NH*SEQ*4;
    float* mxa  = (float*)sm;                 sm += NH*SEQ*4;
    float* imp  = (float*)sm;                 sm += SEQ*4;
    int*   hh   = (int*)sm;                   sm += 256*4;
    float* wk   = (float*)sm;                 sm += NH*SEQ*4;
    float* wv   = (float*)sm;                 sm += NH*SEQ*4;
    float* red  = (float*)sm;                 // 64*SEQ*4 = 512 KB
    float* part = (float*)(base + 56*MB);     // 2048*2048*4 = 16 MB

    // 1. split inputs
    splitx_k<<<SEQ*HID/1024, 256, 0, stream>>>(x, xhi, xlo);
    splitw_k<<<dim3(16,16), 256, 0, stream>>>(Wq, w1hi, w1lo);
    splitw_k<<<dim3(16,16), 256, 0, stream>>>(Wk, w2hi, w2lo);
    splitw_k<<<dim3(16,16), 256, 0, stream>>>(Wv, w3hi, w3lo);

    // 2. projections (bf16x3 MFMA)
    dim3 gG(64, 16);
    gemm_sp<<<gG, 256, 0, stream>>>(xhi, xlo, w1hi, w1lo, nullptr, qsphi, qsplo);
    gemm_sp<<<gG, 256, 0, stream>>>(xhi, xlo, w2hi, w2lo, kf, ksphi, ksplo);
    gemm_sp<<<gG, 256, 0, stream>>>(xhi, xlo, w3hi, w3lo, vf, nullptr, nullptr);

    // 3. Wo split (reuses Wq slot; gemm_q already consumed it)
    splitw_k<<<dim3(16,16), 256, 0, stream>>>(Wo, w1hi, w1lo);

    // 4. score stats + heavy hitters (influence via plain stores + tree reduce)
    score_mfma<<<dim3(NH, SEQ/16), 256, 0, stream>>>(qsphi, qsplo, ksphi, ksplo, ent, mxa, part);
    reduce_infl<<<dim3(SEQ/256, 64), 256, 0, stream>>>(part, red);
    importance_k<<<SEQ/256, 256, 0, stream>>>(ent, mxa, red, imp);
    topk_k<<<SEQ/256, 256, 0, stream>>>(imp, hh);

    // 5. compression weights + cat building (cat arrays reuse ksp slot)
    norms_k<<<NH*SEQ/4, 256, 0, stream>>>(kf, wk);
    norms_k<<<NH*SEQ/4, 256, 0, stream>>>(vf, wv);
    softw_k<<<NH, 256, 0, stream>>>(wk);
    softw_k<<<NH, 256, 0, stream>>>(wv);
    poolk_k<<<NH*LCOMP*HD/256, 256, 0, stream>>>(kf, wk, kchi, kclo);
    poolv_k<<<NH*LCOMP*HD/256, 256, 0, stream>>>(vf, wv, vthi, vtlo);
    padzero_k<<<208, 256, 0, stream>>>(kchi, kclo, vthi, vtlo);
    gather_k<<<NH*NKH*HD/256, 256, 0, stream>>>(kf, vf, hh, kchi, kclo, vthi, vtlo);

    // 6. final attention (writes pre-split ao into xsp slot)
    attn_mfma<<<dim3(NH, SEQ/16), 256, 0, stream>>>(qsphi, qsplo, kchi, kclo, vthi, vtlo, aohi, aolo);

    // 7. output projection
    gemm_sp<<<gG, 256, 0, stream>>>(aohi, aolo, w1hi, w1lo, out, nullptr, nullptr);
}

// Round 7
// 662.669 us; speedup vs baseline: 1.2569x; 1.2569x over previous
//
#include <hip/hip_runtime.h>
#include <math.h>

#define SEQ   2048
#define HID   1024
#define NH    16
#define HD    64
#define NKH   204          // heavy hitters = int(2048*0.1)
#define LCOMP 512          // compressed length = 2048/4
#define NCAT  716          // 204 + 512
#define NCATP 768          // padded to multiple of 64 (52 pad keys)
#define SCALE 0.125f       // 1/sqrt(64)

typedef __attribute__((ext_vector_type(8))) short short8;   // 8 bf16 (4 VGPRs)
typedef __attribute__((ext_vector_type(4))) float f32x4;    // MFMA accumulator

// ---- bf16 split helpers (RNE) -------------------------------------------
__device__ __forceinline__ short f2bf(float f) {
    unsigned u = __builtin_bit_cast(unsigned, f);
    u += 0x7FFFu + ((u >> 16) & 1u);
    return (short)(u >> 16);
}
__device__ __forceinline__ float bf2f(short h) {
    unsigned u = ((unsigned)(unsigned short)h) << 16;
    return __builtin_bit_cast(float, u);
}

// ---------------------------------------------------------------------------
// One-pass splitters: f32 -> bf16 hi/lo.
// ---------------------------------------------------------------------------
__global__ __launch_bounds__(256) void splitx_k(const float* __restrict__ X,
                                                unsigned short* __restrict__ hi,
                                                unsigned short* __restrict__ lo) {
    size_t g = ((size_t)blockIdx.x * 256 + threadIdx.x) * 4;
    float4 v4 = *(const float4*)(X + g);
    ushort4 h4, l4;
    short hb;
    hb = f2bf(v4.x); h4.x = hb; l4.x = (unsigned short)f2bf(v4.x - bf2f(hb));
    hb = f2bf(v4.y); h4.y = hb; l4.y = (unsigned short)f2bf(v4.y - bf2f(hb));
    hb = f2bf(v4.z); h4.z = hb; l4.z = (unsigned short)f2bf(v4.z - bf2f(hb));
    hb = f2bf(v4.w); h4.w = hb; l4.w = (unsigned short)f2bf(v4.w - bf2f(hb));
    *(ushort4*)(hi + g) = h4;
    *(ushort4*)(lo + g) = l4;
}

__global__ __launch_bounds__(256) void splitw_k(const float* __restrict__ W,
                                                unsigned short* __restrict__ hi,
                                                unsigned short* __restrict__ lo) {
    __shared__ float tile[64][65];
    int n0 = blockIdx.x * 64, k0 = blockIdx.y * 64;
    int t = threadIdx.x;
    int r = t >> 4, c4 = (t & 15) * 4;
    #pragma unroll
    for (int i = 0; i < 4; ++i) {
        float4 v4 = *(const float4*)(W + (size_t)(k0 + i*16 + r) * HID + n0 + c4);
        tile[i*16 + r][c4+0] = v4.x; tile[i*16 + r][c4+1] = v4.y;
        tile[i*16 + r][c4+2] = v4.z; tile[i*16 + r][c4+3] = v4.w;
    }
    __syncthreads();
    #pragma unroll
    for (int i = 0; i < 4; ++i) {
        int n = i*16 + r;
        float v0 = tile[c4+0][n], v1 = tile[c4+1][n];
        float v2 = tile[c4+2][n], v3 = tile[c4+3][n];
        ushort4 h4, l4;
        short hb;
        hb = f2bf(v0); h4.x = hb; l4.x = (unsigned short)f2bf(v0 - bf2f(hb));
        hb = f2bf(v1); h4.y = hb; l4.y = (unsigned short)f2bf(v1 - bf2f(hb));
        hb = f2bf(v2); h4.z = hb; l4.z = (unsigned short)f2bf(v2 - bf2f(hb));
        hb = f2bf(v3); h4.w = hb; l4.w = (unsigned short)f2bf(v3 - bf2f(hb));
        size_t o = (size_t)(n0 + n) * HID + k0 + c4;
        *(ushort4*)(hi + o) = h4;
        *(ushort4*)(lo + o) = l4;
    }
}

// ---------------------------------------------------------------------------
// bf16x3 MFMA GEMM (round-5 config: grid (64,8), wave = 32m x 32n, serial
// chains, no prefetch -> VGPR fits the 4-wave occupancy step).
// ---------------------------------------------------------------------------
__global__ __launch_bounds__(256) void gemm_sp(const unsigned short* __restrict__ Ahi,
                                               const unsigned short* __restrict__ Alo,
                                               const unsigned short* __restrict__ Bthi,
                                               const unsigned short* __restrict__ Btlo,
                                               float* __restrict__ Cf,
                                               unsigned short* __restrict__ Hhi,
                                               unsigned short* __restrict__ Hlo) {
    int t = threadIdx.x, lane = t & 63, w = t >> 6;
    int quad = lane >> 4, c16 = lane & 15;
    int m0 = blockIdx.x * 32;
    int nw = blockIdx.y * 128 + w * 32;
    const unsigned short* a0h = Ahi + (size_t)(m0 + c16) * HID;
    const unsigned short* a0l = Alo + (size_t)(m0 + c16) * HID;
    const unsigned short* b0h = Bthi + (size_t)(nw + c16) * HID;
    const unsigned short* b0l = Btlo + (size_t)(nw + c16) * HID;
    f32x4 acc[2][2];
    #pragma unroll
    for (int mt = 0; mt < 2; ++mt)
        #pragma unroll
        for (int nt = 0; nt < 2; ++nt)
            acc[mt][nt] = (f32x4){0.f, 0.f, 0.f, 0.f};
    #pragma unroll 2
    for (int kc = 0; kc < 32; ++kc) {
        int ko = kc * 32 + quad * 8;
        short8 Ah0 = *(const short8*)(a0h + ko);
        short8 Al0 = *(const short8*)(a0l + ko);
        short8 Ah1 = *(const short8*)(a0h + 16 * HID + ko);
        short8 Al1 = *(const short8*)(a0l + 16 * HID + ko);
        #pragma unroll
        for (int nt = 0; nt < 2; ++nt) {
            short8 Bh = *(const short8*)(b0h + nt * 16 * HID + ko);
            short8 Bl = *(const short8*)(b0l + nt * 16 * HID + ko);
            acc[0][nt] = __builtin_amdgcn_mfma_f32_16x16x32_bf16(Ah0, Bh, acc[0][nt], 0, 0, 0);
            acc[0][nt] = __builtin_amdgcn_mfma_f32_16x16x32_bf16(Al0, Bh, acc[0][nt], 0, 0, 0);
            acc[0][nt] = __builtin_amdgcn_mfma_f32_16x16x32_bf16(Ah0, Bl, acc[0][nt], 0, 0, 0);
            acc[1][nt] = __builtin_amdgcn_mfma_f32_16x16x32_bf16(Ah1, Bh, acc[1][nt], 0, 0, 0);
            acc[1][nt] = __builtin_amdgcn_mfma_f32_16x16x32_bf16(Al1, Bh, acc[1][nt], 0, 0, 0);
            acc[1][nt] = __builtin_amdgcn_mfma_f32_16x16x32_bf16(Ah1, Bl, acc[1][nt], 0, 0, 0);
        }
    }
    #pragma unroll
    for (int mt = 0; mt < 2; ++mt)
    #pragma unroll
    for (int nt = 0; nt < 2; ++nt)
    #pragma unroll
    for (int i = 0; i < 4; ++i) {
        int m = m0 + mt*16 + quad*4 + i;
        int n = nw + nt*16 + c16;
        float val = acc[mt][nt][i];
        if (Cf) Cf[(size_t)m * HID + n] = val;
        if (Hhi) {
            int hh_ = n >> 6, d = n & 63;
            size_t o = ((size_t)hh_ * SEQ + m) * HD + d;
            short hb = f2bf(val);
            Hhi[o] = (unsigned short)hb;
            Hlo[o] = (unsigned short)f2bf(val - bf2f(hb));
        }
    }
}

// ---------------------------------------------------------------------------
// Score stats (round-5 structure, VGPR 128) + __expf/__logf fast math +
// atomic-free influence (coalesced slab stores).  Block = (head, 16 q rows),
// wave w owns keys [w*512, +512), 128 scores/lane in VGPRs.
// ---------------------------------------------------------------------------
__global__ __launch_bounds__(256) void score_mfma(const unsigned short* __restrict__ qhi,
                                                  const unsigned short* __restrict__ qlo,
                                                  const unsigned short* __restrict__ khi,
                                                  const unsigned short* __restrict__ klo,
                                                  float* __restrict__ ent,
                                                  float* __restrict__ mxa,
                                                  float* __restrict__ part) {
    __shared__ float redm[4][16], redl[4][16], rede[4][16];
    int h  = blockIdx.x;
    int qb = blockIdx.y;
    int m0 = qb * 16;
    int t  = threadIdx.x;
    int lane = t & 63, w = t >> 6;
    int quad = lane >> 4, c16 = lane & 15;

    const unsigned short* qph = qhi + ((size_t)h * SEQ + m0 + c16) * HD;
    const unsigned short* qpl = qlo + ((size_t)h * SEQ + m0 + c16) * HD;
    short8 Ah0 = *(const short8*)(qph + quad*8);
    short8 Ah1 = *(const short8*)(qph + 32 + quad*8);
    short8 Al0 = *(const short8*)(qpl + quad*8);
    short8 Al1 = *(const short8*)(qpl + 32 + quad*8);

    float sreg[32][4];
    #pragma unroll
    for (int nt = 0; nt < 32; ++nt) {
        int key = (w * 32 + nt) * 16 + c16;
        const unsigned short* kbh = khi + ((size_t)h * SEQ + key) * HD;
        const unsigned short* kbl = klo + ((size_t)h * SEQ + key) * HD;
        short8 Bh0 = *(const short8*)(kbh + quad*8);
        short8 Bh1 = *(const short8*)(kbh + 32 + quad*8);
        short8 Bl0 = *(const short8*)(kbl + quad*8);
        short8 Bl1 = *(const short8*)(kbl + 32 + quad*8);
        f32x4 acc = {0.f, 0.f, 0.f, 0.f};
        acc = __builtin_amdgcn_mfma_f32_16x16x32_bf16(Ah0, Bh0, acc, 0, 0, 0);
        acc = __builtin_amdgcn_mfma_f32_16x16x32_bf16(Al0, Bh0, acc, 0, 0, 0);
        acc = __builtin_amdgcn_mfma_f32_16x16x32_bf16(Ah0, Bl0, acc, 0, 0, 0);
        acc = __builtin_amdgcn_mfma_f32_16x16x32_bf16(Ah1, Bh1, acc, 0, 0, 0);
        acc = __builtin_amdgcn_mfma_f32_16x16x32_bf16(Al1, Bh1, acc, 0, 0, 0);
        acc = __builtin_amdgcn_mfma_f32_16x16x32_bf16(Ah1, Bl1, acc, 0, 0, 0);
        #pragma unroll
        for (int i = 0; i < 4; ++i) sreg[nt][i] = acc[i] * SCALE;
    }

    // ---- global row max ----
    float m[4];
    #pragma unroll
    for (int i = 0; i < 4; ++i) {
        float mm = -1e30f;
        #pragma unroll
        for (int nt = 0; nt < 32; ++nt) mm = fmaxf(mm, sreg[nt][i]);
        #pragma unroll
        for (int off = 1; off <= 8; off <<= 1) mm = fmaxf(mm, __shfl_xor(mm, off));
        m[i] = mm;
    }
    if (c16 == 0) {
        #pragma unroll
        for (int i = 0; i < 4; ++i) redm[w][quad*4 + i] = m[i];
    }
    __syncthreads();
    #pragma unroll
    for (int i = 0; i < 4; ++i) {
        int row = quad*4 + i;
        m[i] = fmaxf(fmaxf(redm[0][row], redm[1][row]),
                     fmaxf(redm[2][row], redm[3][row]));
    }

    // ---- single fast-exp pass: l = sum(t), ee = sum(t*d); sreg <- t ----
    float l[4], ee[4];
    #pragma unroll
    for (int i = 0; i < 4; ++i) {
        float ll = 0.f, e2 = 0.f;
        #pragma unroll
        for (int nt = 0; nt < 32; ++nt) {
            float d = sreg[nt][i] - m[i];
            float tt = __expf(d);
            sreg[nt][i] = tt;
            ll += tt;
            e2 += tt * d;
        }
        #pragma unroll
        for (int off = 1; off <= 8; off <<= 1) {
            ll += __shfl_xor(ll, off);
            e2 += __shfl_xor(e2, off);
        }
        l[i] = ll; ee[i] = e2;
    }
    if (c16 == 0) {
        #pragma unroll
        for (int i = 0; i < 4; ++i) { redl[w][quad*4 + i] = l[i]; rede[w][quad*4 + i] = ee[i]; }
    }
    __syncthreads();
    float inv[4];
    #pragma unroll
    for (int i = 0; i < 4; ++i) {
        int row = quad*4 + i;
        l[i]  = redl[0][row] + redl[1][row] + redl[2][row] + redl[3][row];
        ee[i] = rede[0][row] + rede[1][row] + rede[2][row] + rede[3][row];
        inv[i] = 1.f / l[i];
    }
    if (w == 0 && c16 == 0) {
        #pragma unroll
        for (int i = 0; i < 4; ++i) {
            mxa[h*SEQ + m0 + quad*4 + i] = inv[i];
            ent[h*SEQ + m0 + quad*4 + i] = __logf(l[i]) - ee[i] * inv[i];
        }
    }

    // ---- influence partials: plain coalesced stores, no atomics ----
    float* pslab = part + (size_t)(h * (SEQ/16) + qb) * SEQ;
    #pragma unroll
    for (int nt = 0; nt < 32; ++nt) {
        float cs = sreg[nt][0]*inv[0] + sreg[nt][1]*inv[1]
                 + sreg[nt][2]*inv[2] + sreg[nt][3]*inv[3];
        cs += __shfl_xor(cs, 16);
        cs += __shfl_xor(cs, 32);
        if (lane < 16) pslab[(w*32 + nt)*16 + lane] = cs;
    }
}

// stage-1 influence reduction: red[g][s] = sum of 32 slabs
__global__ __launch_bounds__(256) void reduce_infl(const float* __restrict__ part,
                                                   float* __restrict__ red) {
    int s = blockIdx.x * 256 + threadIdx.x;
    int g = blockIdx.y;
    const float* p = part + (size_t)g * 32 * SEQ + s;
    float a = 0.f;
    #pragma unroll 8
    for (int i = 0; i < 32; ++i) a += p[(size_t)i * SEQ];
    red[(size_t)g * SEQ + s] = a;
}

__global__ __launch_bounds__(256) void importance_k(const float* __restrict__ ent,
                                                    const float* __restrict__ mxa,
                                                    const float* __restrict__ red,
                                                    float* __restrict__ imp) {
    int s = blockIdx.x * 256 + threadIdx.x;
    float es = 0.f, ms = 0.f;
    #pragma unroll
    for (int h = 0; h < NH; ++h) { es += ent[h*SEQ + s]; ms += mxa[h*SEQ + s]; }
    float inf = 0.f;
    #pragma unroll 8
    for (int g = 0; g < 64; ++g) inf += red[(size_t)g * SEQ + s];
    imp[s] = (-0.4f*es + 0.3f*ms + 0.3f*inf) * (1.f/16.f);
}

// Deterministic top-k by rank counting (matches lax.top_k set semantics).
__global__ __launch_bounds__(256) void topk_k(const float* __restrict__ imp,
                                              int* __restrict__ hh) {
    __shared__ float si[SEQ];
    int t = threadIdx.x, s = blockIdx.x * 256 + t;
    for (int i = t; i < SEQ; i += 256) si[i] = imp[i];
    __syncthreads();
    float v = si[s];
    int rank = 0;
    #pragma unroll 1
    for (int i = 0; i < SEQ; ++i) {
        float u = si[i];
        rank += (u > v) || (u == v && i < s);
    }
    if (rank < NKH) hh[rank] = s;
}

// per-(h,s) L2 norm of a 64-dim head vector (one wave each)
__global__ __launch_bounds__(256) void norms_k(const float* __restrict__ x,
                                               float* __restrict__ n) {
    int t = threadIdx.x;
    int wid = blockIdx.x * 4 + (t >> 6);
    int lane = t & 63;
    int h = wid >> 11, s = wid & 2047;
    float v = x[(size_t)s * HID + h * HD + lane];
    float ss = v * v;
    #pragma unroll
    for (int off = 32; off; off >>= 1) ss += __shfl_xor(ss, off);
    if (lane == 0) n[h*SEQ + s] = sqrtf(ss);
}

// in-place softmax over SEQ per head (one block per head)
__global__ __launch_bounds__(256) void softw_k(float* __restrict__ n) {
    __shared__ float red[8];
    int h = blockIdx.x, t = threadIdx.x, lane = t & 63, w = t >> 6;
    float* nh = n + (size_t)h * SEQ;
    float m = -1e30f;
    for (int i = t; i < SEQ; i += 256) m = fmaxf(m, nh[i]);
    #pragma unroll
    for (int off = 32; off; off >>= 1) m = fmaxf(m, __shfl_xor(m, off));
    if (lane == 0) red[w] = m;
    __syncthreads();
    m = fmaxf(fmaxf(red[0], red[1]), fmaxf(red[2], red[3]));
    float z = 0.f;
    for (int i = t; i < SEQ; i += 256) z += __expf(nh[i] - m);
    #pragma unroll
    for (int off = 32; off; off >>= 1) z += __shfl_xor(z, off);
    if (lane == 0) red[4 + w] = z;
    __syncthreads();
    z = red[4] + red[5] + red[6] + red[7];
    for (int i = t; i < SEQ; i += 256) nh[i] = __expf(nh[i] - m) / z;
}

// group-4 weighted pooling of K -> pre-split bf16 [h][key][d]
__global__ __launch_bounds__(256) void poolk_k(const float* __restrict__ src,
                                               const float* __restrict__ w,
                                               unsigned short* __restrict__ hi,
                                               unsigned short* __restrict__ lo) {
    int g = blockIdx.x * 256 + threadIdx.x;
    int d = g & 63, rest = g >> 6;
    int l = rest & 511, h = rest >> 9;
    const float* wp = w + (size_t)h * SEQ + l * 4;
    float w0 = wp[0], w1 = wp[1], w2 = wp[2], w3 = wp[3];
    float wsum = w0 + w1 + w2 + w3 + 1e-8f;
    size_t base = (size_t)(l*4) * HID + h * HD + d;
    float val = (src[base]*w0 + src[base+HID]*w1 + src[base+2*HID]*w2 + src[base+3*HID]*w3) / wsum;
    size_t dst = ((size_t)h * NCATP + NKH + l) * HD + d;
    short hb = f2bf(val);
    hi[dst] = (unsigned short)hb;
    lo[dst] = (unsigned short)f2bf(val - bf2f(hb));
}

// group-4 weighted pooling of V -> pre-split bf16 TRANSPOSED [h][d][key]
__global__ __launch_bounds__(256) void poolv_k(const float* __restrict__ src,
                                               const float* __restrict__ w,
                                               unsigned short* __restrict__ hi,
                                               unsigned short* __restrict__ lo) {
    int g = blockIdx.x * 256 + threadIdx.x;
    int d = g & 63, rest = g >> 6;
    int l = rest & 511, h = rest >> 9;
    const float* wp = w + (size_t)h * SEQ + l * 4;
    float w0 = wp[0], w1 = wp[1], w2 = wp[2], w3 = wp[3];
    float wsum = w0 + w1 + w2 + w3 + 1e-8f;
    size_t base = (size_t)(l*4) * HID + h * HD + d;
    float val = (src[base]*w0 + src[base+HID]*w1 + src[base+2*HID]*w2 + src[base+3*HID]*w3) / wsum;
    size_t dst = ((size_t)h * HD + d) * NCATP + NKH + l;
    short hb = f2bf(val);
    hi[dst] = (unsigned short)hb;
    lo[dst] = (unsigned short)f2bf(val - bf2f(hb));
}

// gather heavy-hitter k/v rows -> pre-split bf16 (K direct, V transposed)
__global__ __launch_bounds__(256) void gather_k(const float* __restrict__ k,
                                                const float* __restrict__ v,
                                                const int* __restrict__ hh,
                                                unsigned short* __restrict__ khi,
                                                unsigned short* __restrict__ klo,
                                                unsigned short* __restrict__ vthi,
                                                unsigned short* __restrict__ vtlo) {
    int g = blockIdx.x * 256 + threadIdx.x;
    int d = g & 63, rest = g >> 6;
    int i = rest % NKH, h = rest / NKH;
    int s = hh[i];
    float kv = k[(size_t)s * HID + h * HD + d];
    float vv = v[(size_t)s * HID + h * HD + d];
    size_t kd = ((size_t)h * NCATP + i) * HD + d;
    size_t vd = ((size_t)h * HD + d) * NCATP + i;
    short hb = f2bf(kv);
    khi[kd] = (unsigned short)hb;
    klo[kd] = (unsigned short)f2bf(kv - bf2f(hb));
    hb = f2bf(vv);
    vthi[vd] = (unsigned short)hb;
    vtlo[vd] = (unsigned short)f2bf(vv - bf2f(hb));
}

// zero the 52 pad keys per head in all four split arrays
__global__ __launch_bounds__(256) void padzero_k(unsigned short* __restrict__ khi,
                                                 unsigned short* __restrict__ klo,
                                                 unsigned short* __restrict__ vthi,
                                                 unsigned short* __restrict__ vtlo) {
    int g = blockIdx.x * 256 + threadIdx.x;
    if (g >= NH * (NCATP - NCAT) * HD) return;
    int d = g & 63, rest = g >> 6;
    int i = rest % (NCATP - NCAT), h = rest / (NCATP - NCAT);
    size_t kd = ((size_t)h * NCATP + NCAT + i) * HD + d;
    size_t vd = ((size_t)h * HD + d) * NCATP + NCAT + i;
    khi[kd] = 0; klo[kd] = 0;
    vthi[vd] = 0; vtlo[vd] = 0;
}

// ---------------------------------------------------------------------------
// Final attention via bf16x3 MFMA (round-5 structure) + __expf.
// ---------------------------------------------------------------------------
__global__ __launch_bounds__(256) void attn_mfma(const unsigned short* __restrict__ qhi,
                                                 const unsigned short* __restrict__ qlo,
                                                 const unsigned short* __restrict__ kchi,
                                                 const unsigned short* __restrict__ kclo,
                                                 const unsigned short* __restrict__ vthi,
                                                 const unsigned short* __restrict__ vtlo,
                                                 unsigned short* __restrict__ aohi,
                                                 unsigned short* __restrict__ aolo) {
    __shared__ unsigned short phi[16][776];   // 24.8 KB
    __shared__ unsigned short plo[16][776];   // 24.8 KB
    __shared__ float redm[4][16], redl[4][16];
    int h  = blockIdx.x;
    int m0 = blockIdx.y * 16;
    int t  = threadIdx.x;
    int lane = t & 63, w = t >> 6;
    int quad = lane >> 4, c16 = lane & 15;

    const unsigned short* qph = qhi + ((size_t)h * SEQ + m0 + c16) * HD;
    const unsigned short* qpl = qlo + ((size_t)h * SEQ + m0 + c16) * HD;
    short8 Ah0 = *(const short8*)(qph + quad*8);
    short8 Ah1 = *(const short8*)(qph + 32 + quad*8);
    short8 Al0 = *(const short8*)(qpl + quad*8);
    short8 Al1 = *(const short8*)(qpl + 32 + quad*8);

    // ---- QK^T: 12 tiles of 16 keys ----
    float sreg[12][4];
    #pragma unroll
    for (int nt = 0; nt < 12; ++nt) {
        int key = w*192 + nt*16 + c16;
        const unsigned short* kbh = kchi + ((size_t)h * NCATP + key) * HD;
        const unsigned short* kbl = kclo + ((size_t)h * NCATP + key) * HD;
        short8 Bh0 = *(const short8*)(kbh + quad*8);
        short8 Bh1 = *(const short8*)(kbh + 32 + quad*8);
        short8 Bl0 = *(const short8*)(kbl + quad*8);
        short8 Bl1 = *(const short8*)(kbl + 32 + quad*8);
        f32x4 acc = {0.f, 0.f, 0.f, 0.f};
        acc = __builtin_amdgcn_mfma_f32_16x16x32_bf16(Ah0, Bh0, acc, 0, 0, 0);
        acc = __builtin_amdgcn_mfma_f32_16x16x32_bf16(Al0, Bh0, acc, 0, 0, 0);
        acc = __builtin_amdgcn_mfma_f32_16x16x32_bf16(Ah0, Bl0, acc, 0, 0, 0);
        acc = __builtin_amdgcn_mfma_f32_16x16x32_bf16(Ah1, Bh1, acc, 0, 0, 0);
        acc = __builtin_amdgcn_mfma_f32_16x16x32_bf16(Al1, Bh1, acc, 0, 0, 0);
        acc = __builtin_amdgcn_mfma_f32_16x16x32_bf16(Ah1, Bl1, acc, 0, 0, 0);
        bool bad = key >= NCAT;
        #pragma unroll
        for (int i = 0; i < 4; ++i)
            sreg[nt][i] = bad ? -1e30f : acc[i] * SCALE;
    }

    // ---- softmax ----
    float m[4], l[4];
    #pragma unroll
    for (int i = 0; i < 4; ++i) {
        float mm = -1e30f;
        #pragma unroll
        for (int nt = 0; nt < 12; ++nt) mm = fmaxf(mm, sreg[nt][i]);
        #pragma unroll
        for (int off = 1; off <= 8; off <<= 1) mm = fmaxf(mm, __shfl_xor(mm, off));
        m[i] = mm;
    }
    if (c16 == 0) {
        #pragma unroll
        for (int i = 0; i < 4; ++i) redm[w][quad*4 + i] = m[i];
    }
    __syncthreads();
    #pragma unroll
    for (int i = 0; i < 4; ++i) {
        int row = quad*4 + i;
        m[i] = fmaxf(fmaxf(redm[0][row], redm[1][row]),
                     fmaxf(redm[2][row], redm[3][row]));
    }
    #pragma unroll
    for (int i = 0; i < 4; ++i) {
        float ll = 0.f;
        #pragma unroll
        for (int nt = 0; nt < 12; ++nt) ll += __expf(sreg[nt][i] - m[i]);
        #pragma unroll
        for (int off = 1; off <= 8; off <<= 1) ll += __shfl_xor(ll, off);
        l[i] = ll;
    }
    if (c16 == 0) {
        #pragma unroll
        for (int i = 0; i < 4; ++i) redl[w][quad*4 + i] = l[i];
    }
    __syncthreads();
    float inv[4];
    #pragma unroll
    for (int i = 0; i < 4; ++i) {
        int row = quad*4 + i;
        inv[i] = 1.f / (redl[0][row] + redl[1][row] + redl[2][row] + redl[3][row]);
    }

    // ---- probs -> LDS, pre-split bf16 ----
    #pragma unroll
    for (int nt = 0; nt < 12; ++nt) {
        int key = w*192 + nt*16 + c16;
        #pragma unroll
        for (int i = 0; i < 4; ++i) {
            float p = __expf(sreg[nt][i] - m[i]) * inv[i];
            short ph = f2bf(p);
            phi[quad*4 + i][key] = (unsigned short)ph;
            plo[quad*4 + i][key] = (unsigned short)f2bf(p - bf2f(ph));
        }
    }
    __syncthreads();

    // ---- PV: wave w computes dims [w*16, w*16+16) over all 768 keys ----
    int dim = w*16 + c16;
    const unsigned short* vh = vthi + ((size_t)h * HD + dim) * NCATP;
    const unsigned short* vl = vtlo + ((size_t)h * HD + dim) * NCATP;
    f32x4 ohh = {0.f,0.f,0.f,0.f}, olh = {0.f,0.f,0.f,0.f}, ohl = {0.f,0.f,0.f,0.f};
    #pragma unroll 4
    for (int s = 0; s < 24; ++s) {
        int k0 = s*32 + quad*8;
        short8 Ph = *(const short8*)&phi[c16][k0];
        short8 Pl = *(const short8*)&plo[c16][k0];
        short8 Vh = *(const short8*)(vh + k0);
        short8 Vl = *(const short8*)(vl + k0);
        ohh = __builtin_amdgcn_mfma_f32_16x16x32_bf16(Ph, Vh, ohh, 0, 0, 0);
        olh = __builtin_amdgcn_mfma_f32_16x16x32_bf16(Pl, Vh, olh, 0, 0, 0);
        ohl = __builtin_amdgcn_mfma_f32_16x16x32_bf16(Ph, Vl, ohl, 0, 0, 0);
    }
    #pragma unroll
    for (int i = 0; i < 4; ++i) {
        float val = ohh[i] + olh[i] + ohl[i];
        size_t o = (size_t)(m0 + quad*4 + i) * HID + h * HD + dim;
        short hb = f2bf(val);
        aohi[o] = (unsigned short)hb;
        aolo[o] = (unsigned short)f2bf(val - bf2f(hb));
    }
}

// ---------------------------------------------------------------------------
extern "C" void kernel_launch(void* const* d_in, const int* in_sizes, int n_in,
                              void* d_out, int out_size, void* d_ws, size_t ws_size,
                              hipStream_t stream) {
    const float* x  = (const float*)d_in[0];
    const float* Wq = (const float*)d_in[1];
    const float* Wk = (const float*)d_in[2];
    const float* Wv = (const float*)d_in[3];
    const float* Wo = (const float*)d_in[4];
    float* out = (float*)d_out;

    char* base = (char*)d_ws;                       // ~72.5 MB total
    const size_t MB = 1u << 20;
    float* kf = (float*)(base + 0);                 // 8 MB
    float* vf = (float*)(base + 8*MB);              // 8 MB
    unsigned short* xhi = (unsigned short*)(base + 16*MB);   // 4 MB
    unsigned short* xlo = (unsigned short*)(base + 20*MB);   // 4 MB
    unsigned short* w1hi = (unsigned short*)(base + 24*MB);  // 2 MB (Wq, later Wo)
    unsigned short* w1lo = (unsigned short*)(base + 26*MB);
    unsigned short* w2hi = (unsigned short*)(base + 28*MB);  // Wk
    unsigned short* w2lo = (unsigned short*)(base + 30*MB);
    unsigned short* w3hi = (unsigned short*)(base + 32*MB);  // Wv
    unsigned short* w3lo = (unsigned short*)(base + 34*MB);
    unsigned short* qsphi = (unsigned short*)(base + 36*MB); // 4 MB [h][s][d]
    unsigned short* qsplo = (unsigned short*)(base + 40*MB);
    unsigned short* ksphi = (unsigned short*)(base + 44*MB); // 4 MB [h][s][d]
    unsigned short* ksplo = (unsigned short*)(base + 48*MB);
    // aliases (ordered reuse, safe on an in-order stream):
    unsigned short* aohi = xhi;                     // after QKV gemms read xsp
    unsigned short* aolo = xlo;
    const size_t CATB = (size_t)NH * NCATP * HD * 2; // 1.5 MB
    unsigned short* kchi = (unsigned short*)(base + 44*MB);          // after score_mfma
    unsigned short* kclo = (unsigned short*)(base + 44*MB + CATB);
    unsigned short* vthi = (unsigned short*)(base + 44*MB + 2*CATB);
    unsigned short* vtlo = (unsigned short*)(base + 44*MB + 3*CATB);
    // small buffers
    char* sm = base + 52*MB;
    float* ent  = (float*)sm;                 sm += NH*SEQ*4;
    float* mxa  = (float*)sm;                 sm += NH*SEQ*4;
    float* imp  = (float*)sm;                 sm += SEQ*4;
    int*   hh   = (int*)sm;                   sm += 256*4;
    float* wk   = (float*)sm;                 sm += NH*SEQ*4;
    float* wv   = (float*)sm;                 sm += NH*SEQ*4;
    float* red  = (float*)sm;                 // 64*SEQ*4 = 512 KB
    float* part = (float*)(base + 56*MB);     // 2048*2048*4 = 16 MB

    // 1. split inputs
    splitx_k<<<SEQ*HID/1024, 256, 0, stream>>>(x, xhi, xlo);
    splitw_k<<<dim3(16,16), 256, 0, stream>>>(Wq, w1hi, w1lo);
    splitw_k<<<dim3(16,16), 256, 0, stream>>>(Wk, w2hi, w2lo);
    splitw_k<<<dim3(16,16), 256, 0, stream>>>(Wv, w3hi, w3lo);

    // 2. projections (bf16x3 MFMA)
    dim3 gG(64, 8);
    gemm_sp<<<gG, 256, 0, stream>>>(xhi, xlo, w1hi, w1lo, nullptr, qsphi, qsplo);
    gemm_sp<<<gG, 256, 0, stream>>>(xhi, xlo, w2hi, w2lo, kf, ksphi, ksplo);
    gemm_sp<<<gG, 256, 0, stream>>>(xhi, xlo, w3hi, w3lo, vf, nullptr, nullptr);

    // 3. Wo split (reuses Wq slot; gemm_q already consumed it)
    splitw_k<<<dim3(16,16), 256, 0, stream>>>(Wo, w1hi, w1lo);

    // 4. score stats + heavy hitters (influence via plain stores + tree reduce)
    score_mfma<<<dim3(NH, SEQ/16), 256, 0, stream>>>(qsphi, qsplo, ksphi, ksplo, ent, mxa, part);
    reduce_infl<<<dim3(SEQ/256, 64), 256, 0, stream>>>(part, red);
    importance_k<<<SEQ/256, 256, 0, stream>>>(ent, mxa, red, imp);
    topk_k<<<SEQ/256, 256, 0, stream>>>(imp, hh);

    // 5. compression weights + cat building (cat arrays reuse ksp slot)
    norms_k<<<NH*SEQ/4, 256, 0, stream>>>(kf, wk);
    norms_k<<<NH*SEQ/4, 256, 0, stream>>>(vf, wv);
    softw_k<<<NH, 256, 0, stream>>>(wk);
    softw_k<<<NH, 256, 0, stream>>>(wv);
    poolk_k<<<NH*LCOMP*HD/256, 256, 0, stream>>>(kf, wk, kchi, kclo);
    poolv_k<<<NH*LCOMP*HD/256, 256, 0, stream>>>(vf, wv, vthi, vtlo);
    padzero_k<<<208, 256, 0, stream>>>(kchi, kclo, vthi, vtlo);
    gather_k<<<NH*NKH*HD/256, 256, 0, stream>>>(kf, vf, hh, kchi, kclo, vthi, vtlo);

    // 6. final attention (writes pre-split ao into xsp slot)
    attn_mfma<<<dim3(NH, SEQ/16), 256, 0, stream>>>(qsphi, qsplo, kchi, kclo, vthi, vtlo, aohi, aolo);

    // 7. output projection
    gemm_sp<<<gG, 256, 0, stream>>>(aohi, aolo, w1hi, w1lo, out, nullptr, nullptr);
}

// Round 8
// 657.080 us; speedup vs baseline: 1.2676x; 1.0085x over previous
//
#include <hip/hip_runtime.h>
#include <hip/hip_fp16.h>
#include <math.h>

#define SEQ   2048
#define HID   1024
#define NH    16
#define HD    64
#define NKH   204          // heavy hitters = int(2048*0.1)
#define LCOMP 512          // compressed length = 2048/4
#define NCAT  716          // 204 + 512
#define NCATP 768          // padded to multiple of 64 (52 pad keys)
#define SCALE 0.125f       // 1/sqrt(64)

typedef __attribute__((ext_vector_type(8))) short short8;   // 8 bf16 (4 VGPRs)
typedef __attribute__((ext_vector_type(4))) float f32x4;    // MFMA accumulator

// ---- bf16 split helpers (RNE) -------------------------------------------
__device__ __forceinline__ short f2bf(float f) {
    unsigned u = __builtin_bit_cast(unsigned, f);
    u += 0x7FFFu + ((u >> 16) & 1u);
    return (short)(u >> 16);
}
__device__ __forceinline__ float bf2f(short h) {
    unsigned u = ((unsigned)(unsigned short)h) << 16;
    return __builtin_bit_cast(float, u);
}

// ---------------------------------------------------------------------------
// One-pass splitters: f32 -> bf16 hi/lo.
// ---------------------------------------------------------------------------
__global__ __launch_bounds__(256) void splitx_k(const float* __restrict__ X,
                                                unsigned short* __restrict__ hi,
                                                unsigned short* __restrict__ lo) {
    size_t g = ((size_t)blockIdx.x * 256 + threadIdx.x) * 4;
    float4 v4 = *(const float4*)(X + g);
    ushort4 h4, l4;
    short hb;
    hb = f2bf(v4.x); h4.x = hb; l4.x = (unsigned short)f2bf(v4.x - bf2f(hb));
    hb = f2bf(v4.y); h4.y = hb; l4.y = (unsigned short)f2bf(v4.y - bf2f(hb));
    hb = f2bf(v4.z); h4.z = hb; l4.z = (unsigned short)f2bf(v4.z - bf2f(hb));
    hb = f2bf(v4.w); h4.w = hb; l4.w = (unsigned short)f2bf(v4.w - bf2f(hb));
    *(ushort4*)(hi + g) = h4;
    *(ushort4*)(lo + g) = l4;
}

__global__ __launch_bounds__(256) void splitw_k(const float* __restrict__ W,
                                                unsigned short* __restrict__ hi,
                                                unsigned short* __restrict__ lo) {
    __shared__ float tile[64][65];
    int n0 = blockIdx.x * 64, k0 = blockIdx.y * 64;
    int t = threadIdx.x;
    int r = t >> 4, c4 = (t & 15) * 4;
    #pragma unroll
    for (int i = 0; i < 4; ++i) {
        float4 v4 = *(const float4*)(W + (size_t)(k0 + i*16 + r) * HID + n0 + c4);
        tile[i*16 + r][c4+0] = v4.x; tile[i*16 + r][c4+1] = v4.y;
        tile[i*16 + r][c4+2] = v4.z; tile[i*16 + r][c4+3] = v4.w;
    }
    __syncthreads();
    #pragma unroll
    for (int i = 0; i < 4; ++i) {
        int n = i*16 + r;
        float v0 = tile[c4+0][n], v1 = tile[c4+1][n];
        float v2 = tile[c4+2][n], v3 = tile[c4+3][n];
        ushort4 h4, l4;
        short hb;
        hb = f2bf(v0); h4.x = hb; l4.x = (unsigned short)f2bf(v0 - bf2f(hb));
        hb = f2bf(v1); h4.y = hb; l4.y = (unsigned short)f2bf(v1 - bf2f(hb));
        hb = f2bf(v2); h4.z = hb; l4.z = (unsigned short)f2bf(v2 - bf2f(hb));
        hb = f2bf(v3); h4.w = hb; l4.w = (unsigned short)f2bf(v3 - bf2f(hb));
        size_t o = (size_t)(n0 + n) * HID + k0 + c4;
        *(ushort4*)(hi + o) = h4;
        *(ushort4*)(lo + o) = l4;
    }
}

// ---------------------------------------------------------------------------
// Fused QKV projection: C[2048,3072] = x[2048,1024] @ [Wq|Wk|Wv].
// Grid (64,24), wave = 32m x 32n; seg = by>>3 picks q/k/v epilogue.
// ---------------------------------------------------------------------------
__global__ __launch_bounds__(256) void gemm_qkv(const unsigned short* __restrict__ Ahi,
                                                const unsigned short* __restrict__ Alo,
                                                const unsigned short* __restrict__ Bthi,
                                                const unsigned short* __restrict__ Btlo,
                                                unsigned short* __restrict__ qhi,
                                                unsigned short* __restrict__ qlo,
                                                float* __restrict__ kf,
                                                unsigned short* __restrict__ khi,
                                                unsigned short* __restrict__ klo,
                                                float* __restrict__ vf) {
    int t = threadIdx.x, lane = t & 63, w = t >> 6;
    int quad = lane >> 4, c16 = lane & 15;
    int m0 = blockIdx.x * 32;
    int nw = blockIdx.y * 128 + w * 32;
    const unsigned short* a0h = Ahi + (size_t)(m0 + c16) * HID;
    const unsigned short* a0l = Alo + (size_t)(m0 + c16) * HID;
    const unsigned short* b0h = Bthi + (size_t)(nw + c16) * HID;
    const unsigned short* b0l = Btlo + (size_t)(nw + c16) * HID;
    f32x4 acc[2][2];
    #pragma unroll
    for (int mt = 0; mt < 2; ++mt)
        #pragma unroll
        for (int nt = 0; nt < 2; ++nt)
            acc[mt][nt] = (f32x4){0.f, 0.f, 0.f, 0.f};
    #pragma unroll 2
    for (int kc = 0; kc < 32; ++kc) {
        int ko = kc * 32 + quad * 8;
        short8 Ah0 = *(const short8*)(a0h + ko);
        short8 Al0 = *(const short8*)(a0l + ko);
        short8 Ah1 = *(const short8*)(a0h + 16 * HID + ko);
        short8 Al1 = *(const short8*)(a0l + 16 * HID + ko);
        #pragma unroll
        for (int nt = 0; nt < 2; ++nt) {
            short8 Bh = *(const short8*)(b0h + nt * 16 * HID + ko);
            short8 Bl = *(const short8*)(b0l + nt * 16 * HID + ko);
            acc[0][nt] = __builtin_amdgcn_mfma_f32_16x16x32_bf16(Ah0, Bh, acc[0][nt], 0, 0, 0);
            acc[0][nt] = __builtin_amdgcn_mfma_f32_16x16x32_bf16(Al0, Bh, acc[0][nt], 0, 0, 0);
            acc[0][nt] = __builtin_amdgcn_mfma_f32_16x16x32_bf16(Ah0, Bl, acc[0][nt], 0, 0, 0);
            acc[1][nt] = __builtin_amdgcn_mfma_f32_16x16x32_bf16(Ah1, Bh, acc[1][nt], 0, 0, 0);
            acc[1][nt] = __builtin_amdgcn_mfma_f32_16x16x32_bf16(Al1, Bh, acc[1][nt], 0, 0, 0);
            acc[1][nt] = __builtin_amdgcn_mfma_f32_16x16x32_bf16(Ah1, Bl, acc[1][nt], 0, 0, 0);
        }
    }
    int seg = blockIdx.y >> 3;     // 0=q, 1=k, 2=v (wave-uniform)
    #pragma unroll
    for (int mt = 0; mt < 2; ++mt)
    #pragma unroll
    for (int nt = 0; nt < 2; ++nt)
    #pragma unroll
    for (int i = 0; i < 4; ++i) {
        int m = m0 + mt*16 + quad*4 + i;
        int nl = (nw + nt*16 + c16) & 1023;
        float val = acc[mt][nt][i];
        if (seg == 0) {
            size_t o = ((size_t)(nl >> 6) * SEQ + m) * HD + (nl & 63);
            short hb = f2bf(val);
            qhi[o] = (unsigned short)hb;
            qlo[o] = (unsigned short)f2bf(val - bf2f(hb));
        } else if (seg == 1) {
            kf[(size_t)m * HID + nl] = val;
            size_t o = ((size_t)(nl >> 6) * SEQ + m) * HD + (nl & 63);
            short hb = f2bf(val);
            khi[o] = (unsigned short)hb;
            klo[o] = (unsigned short)f2bf(val - bf2f(hb));
        } else {
            vf[(size_t)m * HID + nl] = val;
        }
    }
}

// ---------------------------------------------------------------------------
// bf16x3 MFMA GEMM (for output projection): grid (64,8), wave = 32m x 32n.
// ---------------------------------------------------------------------------
__global__ __launch_bounds__(256) void gemm_sp(const unsigned short* __restrict__ Ahi,
                                               const unsigned short* __restrict__ Alo,
                                               const unsigned short* __restrict__ Bthi,
                                               const unsigned short* __restrict__ Btlo,
                                               float* __restrict__ Cf) {
    int t = threadIdx.x, lane = t & 63, w = t >> 6;
    int quad = lane >> 4, c16 = lane & 15;
    int m0 = blockIdx.x * 32;
    int nw = blockIdx.y * 128 + w * 32;
    const unsigned short* a0h = Ahi + (size_t)(m0 + c16) * HID;
    const unsigned short* a0l = Alo + (size_t)(m0 + c16) * HID;
    const unsigned short* b0h = Bthi + (size_t)(nw + c16) * HID;
    const unsigned short* b0l = Btlo + (size_t)(nw + c16) * HID;
    f32x4 acc[2][2];
    #pragma unroll
    for (int mt = 0; mt < 2; ++mt)
        #pragma unroll
        for (int nt = 0; nt < 2; ++nt)
            acc[mt][nt] = (f32x4){0.f, 0.f, 0.f, 0.f};
    #pragma unroll 2
    for (int kc = 0; kc < 32; ++kc) {
        int ko = kc * 32 + quad * 8;
        short8 Ah0 = *(const short8*)(a0h + ko);
        short8 Al0 = *(const short8*)(a0l + ko);
        short8 Ah1 = *(const short8*)(a0h + 16 * HID + ko);
        short8 Al1 = *(const short8*)(a0l + 16 * HID + ko);
        #pragma unroll
        for (int nt = 0; nt < 2; ++nt) {
            short8 Bh = *(const short8*)(b0h + nt * 16 * HID + ko);
            short8 Bl = *(const short8*)(b0l + nt * 16 * HID + ko);
            acc[0][nt] = __builtin_amdgcn_mfma_f32_16x16x32_bf16(Ah0, Bh, acc[0][nt], 0, 0, 0);
            acc[0][nt] = __builtin_amdgcn_mfma_f32_16x16x32_bf16(Al0, Bh, acc[0][nt], 0, 0, 0);
            acc[0][nt] = __builtin_amdgcn_mfma_f32_16x16x32_bf16(Ah0, Bl, acc[0][nt], 0, 0, 0);
            acc[1][nt] = __builtin_amdgcn_mfma_f32_16x16x32_bf16(Ah1, Bh, acc[1][nt], 0, 0, 0);
            acc[1][nt] = __builtin_amdgcn_mfma_f32_16x16x32_bf16(Al1, Bh, acc[1][nt], 0, 0, 0);
            acc[1][nt] = __builtin_amdgcn_mfma_f32_16x16x32_bf16(Ah1, Bl, acc[1][nt], 0, 0, 0);
        }
    }
    #pragma unroll
    for (int mt = 0; mt < 2; ++mt)
    #pragma unroll
    for (int nt = 0; nt < 2; ++nt)
    #pragma unroll
    for (int i = 0; i < 4; ++i) {
        int m = m0 + mt*16 + quad*4 + i;
        int n = nw + nt*16 + c16;
        Cf[(size_t)m * HID + n] = acc[mt][nt][i];
    }
}

// ---------------------------------------------------------------------------
// Score stats v4: two-pass recompute, NO score storage (VGPR-light, loads
// pipeline freely).  Scores are bounded (|s|<~6) so exp needs no max-sub;
// m tracked only for mxa.  Block = (head, 32 q rows), wave w owns keys
// [w*512,+512).  Pass 2 recomputes QK and emits f16 influence col-sums.
// ---------------------------------------------------------------------------
__global__ __launch_bounds__(256) void score_mfma(const unsigned short* __restrict__ qhi,
                                                  const unsigned short* __restrict__ qlo,
                                                  const unsigned short* __restrict__ khi,
                                                  const unsigned short* __restrict__ klo,
                                                  float* __restrict__ ent,
                                                  float* __restrict__ mxa,
                                                  __half* __restrict__ part) {
    __shared__ float redm[4][32], redl[4][32], rede[4][32];
    int h  = blockIdx.x;
    int qb = blockIdx.y;
    int m0 = qb * 32;
    int t  = threadIdx.x;
    int lane = t & 63, w = t >> 6;
    int quad = lane >> 4, c16 = lane & 15;

    // A fragments for two 16-row tiles
    short8 Ah0[2], Ah1[2], Al0[2], Al1[2];
    #pragma unroll
    for (int rt = 0; rt < 2; ++rt) {
        const unsigned short* qph = qhi + ((size_t)h * SEQ + m0 + rt*16 + c16) * HD;
        const unsigned short* qpl = qlo + ((size_t)h * SEQ + m0 + rt*16 + c16) * HD;
        Ah0[rt] = *(const short8*)(qph + quad*8);
        Ah1[rt] = *(const short8*)(qph + 32 + quad*8);
        Al0[rt] = *(const short8*)(qpl + quad*8);
        Al1[rt] = *(const short8*)(qpl + 32 + quad*8);
    }

    // ---- pass 1: stats only ----
    float l[2][4] = {}, ee[2][4] = {};
    float mx[2][4] = {{-1e30f,-1e30f,-1e30f,-1e30f},{-1e30f,-1e30f,-1e30f,-1e30f}};
    #pragma unroll
    for (int nt = 0; nt < 32; ++nt) {
        int key = (w * 32 + nt) * 16 + c16;
        const unsigned short* kbh = khi + ((size_t)h * SEQ + key) * HD;
        const unsigned short* kbl = klo + ((size_t)h * SEQ + key) * HD;
        short8 Bh0 = *(const short8*)(kbh + quad*8);
        short8 Bh1 = *(const short8*)(kbh + 32 + quad*8);
        short8 Bl0 = *(const short8*)(kbl + quad*8);
        short8 Bl1 = *(const short8*)(kbl + 32 + quad*8);
        #pragma unroll
        for (int rt = 0; rt < 2; ++rt) {
            f32x4 acc = {0.f, 0.f, 0.f, 0.f};
            acc = __builtin_amdgcn_mfma_f32_16x16x32_bf16(Ah0[rt], Bh0, acc, 0, 0, 0);
            acc = __builtin_amdgcn_mfma_f32_16x16x32_bf16(Al0[rt], Bh0, acc, 0, 0, 0);
            acc = __builtin_amdgcn_mfma_f32_16x16x32_bf16(Ah0[rt], Bl0, acc, 0, 0, 0);
            acc = __builtin_amdgcn_mfma_f32_16x16x32_bf16(Ah1[rt], Bh1, acc, 0, 0, 0);
            acc = __builtin_amdgcn_mfma_f32_16x16x32_bf16(Al1[rt], Bh1, acc, 0, 0, 0);
            acc = __builtin_amdgcn_mfma_f32_16x16x32_bf16(Ah1[rt], Bl1, acc, 0, 0, 0);
            #pragma unroll
            for (int i = 0; i < 4; ++i) {
                float s = acc[i] * SCALE;
                float tt = __expf(s);          // safe: |s| << 88
                l[rt][i] += tt;
                ee[rt][i] += tt * s;
                mx[rt][i] = fmaxf(mx[rt][i], s);
            }
        }
    }
    // reduce over the 16 lanes sharing rows (c16 groups)
    #pragma unroll
    for (int rt = 0; rt < 2; ++rt)
    #pragma unroll
    for (int i = 0; i < 4; ++i) {
        #pragma unroll
        for (int off = 1; off <= 8; off <<= 1) {
            l[rt][i]  += __shfl_xor(l[rt][i], off);
            ee[rt][i] += __shfl_xor(ee[rt][i], off);
            mx[rt][i]  = fmaxf(mx[rt][i], __shfl_xor(mx[rt][i], off));
        }
    }
    if (c16 == 0) {
        #pragma unroll
        for (int rt = 0; rt < 2; ++rt)
        #pragma unroll
        for (int i = 0; i < 4; ++i) {
            int row = rt*16 + quad*4 + i;
            redl[w][row] = l[rt][i];
            rede[w][row] = ee[rt][i];
            redm[w][row] = mx[rt][i];
        }
    }
    __syncthreads();
    // every lane combines the 4 wave-partials for ITS rows
    float inv[2][4];
    #pragma unroll
    for (int rt = 0; rt < 2; ++rt)
    #pragma unroll
    for (int i = 0; i < 4; ++i) {
        int row = rt*16 + quad*4 + i;
        float lf = redl[0][row] + redl[1][row] + redl[2][row] + redl[3][row];
        inv[rt][i] = 1.f / lf;
        if (w == 0 && c16 == 0) {
            float eef = rede[0][row] + rede[1][row] + rede[2][row] + rede[3][row];
            float mf  = fmaxf(fmaxf(redm[0][row], redm[1][row]),
                              fmaxf(redm[2][row], redm[3][row]));
            mxa[h*SEQ + m0 + row] = __expf(mf) * inv[rt][i];
            ent[h*SEQ + m0 + row] = __logf(lf) - eef * inv[rt][i];
        }
    }

    // ---- pass 2: recompute QK, emit influence column sums (f16) ----
    __half* pslab = part + (size_t)(h * (SEQ/32) + qb) * SEQ;
    #pragma unroll
    for (int nt = 0; nt < 32; ++nt) {
        int key = (w * 32 + nt) * 16 + c16;
        const unsigned short* kbh = khi + ((size_t)h * SEQ + key) * HD;
        const unsigned short* kbl = klo + ((size_t)h * SEQ + key) * HD;
        short8 Bh0 = *(const short8*)(kbh + quad*8);
        short8 Bh1 = *(const short8*)(kbh + 32 + quad*8);
        short8 Bl0 = *(const short8*)(kbl + quad*8);
        short8 Bl1 = *(const short8*)(kbl + 32 + quad*8);
        float cs = 0.f;
        #pragma unroll
        for (int rt = 0; rt < 2; ++rt) {
            f32x4 acc = {0.f, 0.f, 0.f, 0.f};
            acc = __builtin_amdgcn_mfma_f32_16x16x32_bf16(Ah0[rt], Bh0, acc, 0, 0, 0);
            acc = __builtin_amdgcn_mfma_f32_16x16x32_bf16(Al0[rt], Bh0, acc, 0, 0, 0);
            acc = __builtin_amdgcn_mfma_f32_16x16x32_bf16(Ah0[rt], Bl0, acc, 0, 0, 0);
            acc = __builtin_amdgcn_mfma_f32_16x16x32_bf16(Ah1[rt], Bh1, acc, 0, 0, 0);
            acc = __builtin_amdgcn_mfma_f32_16x16x32_bf16(Al1[rt], Bh1, acc, 0, 0, 0);
            acc = __builtin_amdgcn_mfma_f32_16x16x32_bf16(Ah1[rt], Bl1, acc, 0, 0, 0);
            #pragma unroll
            for (int i = 0; i < 4; ++i)
                cs += __expf(acc[i] * SCALE) * inv[rt][i];
        }
        cs += __shfl_xor(cs, 16);
        cs += __shfl_xor(cs, 32);           // sum over all 32 rows (4 quads)
        if (lane < 16) pslab[(w*32 + nt)*16 + lane] = __float2half(cs);
    }
}

// stage-1 influence reduction: red[g][s] = sum of 16 slabs (f16 -> f32)
__global__ __launch_bounds__(256) void reduce_infl(const __half* __restrict__ part,
                                                   float* __restrict__ red) {
    int s = blockIdx.x * 256 + threadIdx.x;
    int g = blockIdx.y;
    const __half* p = part + (size_t)g * 16 * SEQ + s;
    float a = 0.f;
    #pragma unroll
    for (int i = 0; i < 16; ++i) a += __half2float(p[(size_t)i * SEQ]);
    red[(size_t)g * SEQ + s] = a;
}

__global__ __launch_bounds__(256) void importance_k(const float* __restrict__ ent,
                                                    const float* __restrict__ mxa,
                                                    const float* __restrict__ red,
                                                    float* __restrict__ imp) {
    int s = blockIdx.x * 256 + threadIdx.x;
    float es = 0.f, ms = 0.f;
    #pragma unroll
    for (int h = 0; h < NH; ++h) { es += ent[h*SEQ + s]; ms += mxa[h*SEQ + s]; }
    float inf = 0.f;
    #pragma unroll 8
    for (int g = 0; g < 64; ++g) inf += red[(size_t)g * SEQ + s];
    imp[s] = (-0.4f*es + 0.3f*ms + 0.3f*inf) * (1.f/16.f);
}

// Deterministic top-k by rank counting (matches lax.top_k set semantics).
__global__ __launch_bounds__(256) void topk_k(const float* __restrict__ imp,
                                              int* __restrict__ hh) {
    __shared__ float si[SEQ];
    int t = threadIdx.x, s = blockIdx.x * 256 + t;
    for (int i = t; i < SEQ; i += 256) si[i] = imp[i];
    __syncthreads();
    float v = si[s];
    int rank = 0;
    #pragma unroll 1
    for (int i = 0; i < SEQ; ++i) {
        float u = si[i];
        rank += (u > v) || (u == v && i < s);
    }
    if (rank < NKH) hh[rank] = s;
}

// per-(h,s) L2 norm of a 64-dim head vector (one wave each)
__global__ __launch_bounds__(256) void norms_k(const float* __restrict__ x,
                                               float* __restrict__ n) {
    int t = threadIdx.x;
    int wid = blockIdx.x * 4 + (t >> 6);
    int lane = t & 63;
    int h = wid >> 11, s = wid & 2047;
    float v = x[(size_t)s * HID + h * HD + lane];
    float ss = v * v;
    #pragma unroll
    for (int off = 32; off; off >>= 1) ss += __shfl_xor(ss, off);
    if (lane == 0) n[h*SEQ + s] = sqrtf(ss);
}

// in-place softmax over SEQ per head (one block per head)
__global__ __launch_bounds__(256) void softw_k(float* __restrict__ n) {
    __shared__ float red[8];
    int h = blockIdx.x, t = threadIdx.x, lane = t & 63, w = t >> 6;
    float* nh = n + (size_t)h * SEQ;
    float m = -1e30f;
    for (int i = t; i < SEQ; i += 256) m = fmaxf(m, nh[i]);
    #pragma unroll
    for (int off = 32; off; off >>= 1) m = fmaxf(m, __shfl_xor(m, off));
    if (lane == 0) red[w] = m;
    __syncthreads();
    m = fmaxf(fmaxf(red[0], red[1]), fmaxf(red[2], red[3]));
    float z = 0.f;
    for (int i = t; i < SEQ; i += 256) z += __expf(nh[i] - m);
    #pragma unroll
    for (int off = 32; off; off >>= 1) z += __shfl_xor(z, off);
    if (lane == 0) red[4 + w] = z;
    __syncthreads();
    z = red[4] + red[5] + red[6] + red[7];
    for (int i = t; i < SEQ; i += 256) nh[i] = __expf(nh[i] - m) / z;
}

// group-4 weighted pooling of K -> pre-split bf16 [h][key][d]
__global__ __launch_bounds__(256) void poolk_k(const float* __restrict__ src,
                                               const float* __restrict__ w,
                                               unsigned short* __restrict__ hi,
                                               unsigned short* __restrict__ lo) {
    int g = blockIdx.x * 256 + threadIdx.x;
    int d = g & 63, rest = g >> 6;
    int l = rest & 511, h = rest >> 9;
    const float* wp = w + (size_t)h * SEQ + l * 4;
    float w0 = wp[0], w1 = wp[1], w2 = wp[2], w3 = wp[3];
    float wsum = w0 + w1 + w2 + w3 + 1e-8f;
    size_t base = (size_t)(l*4) * HID + h * HD + d;
    float val = (src[base]*w0 + src[base+HID]*w1 + src[base+2*HID]*w2 + src[base+3*HID]*w3) / wsum;
    size_t dst = ((size_t)h * NCATP + NKH + l) * HD + d;
    short hb = f2bf(val);
    hi[dst] = (unsigned short)hb;
    lo[dst] = (unsigned short)f2bf(val - bf2f(hb));
}

// group-4 weighted pooling of V -> pre-split bf16 TRANSPOSED [h][d][key]
__global__ __launch_bounds__(256) void poolv_k(const float* __restrict__ src,
                                               const float* __restrict__ w,
                                               unsigned short* __restrict__ hi,
                                               unsigned short* __restrict__ lo) {
    int g = blockIdx.x * 256 + threadIdx.x;
    int d = g & 63, rest = g >> 6;
    int l = rest & 511, h = rest >> 9;
    const float* wp = w + (size_t)h * SEQ + l * 4;
    float w0 = wp[0], w1 = wp[1], w2 = wp[2], w3 = wp[3];
    float wsum = w0 + w1 + w2 + w3 + 1e-8f;
    size_t base = (size_t)(l*4) * HID + h * HD + d;
    float val = (src[base]*w0 + src[base+HID]*w1 + src[base+2*HID]*w2 + src[base+3*HID]*w3) / wsum;
    size_t dst = ((size_t)h * HD + d) * NCATP + NKH + l;
    short hb = f2bf(val);
    hi[dst] = (unsigned short)hb;
    lo[dst] = (unsigned short)f2bf(val - bf2f(hb));
}

// gather heavy-hitter k/v rows -> pre-split bf16 (K direct, V transposed)
__global__ __launch_bounds__(256) void gather_k(const float* __restrict__ k,
                                                const float* __restrict__ v,
                                                const int* __restrict__ hh,
                                                unsigned short* __restrict__ khi,
                                                unsigned short* __restrict__ klo,
                                                unsigned short* __restrict__ vthi,
                                                unsigned short* __restrict__ vtlo) {
    int g = blockIdx.x * 256 + threadIdx.x;
    int d = g & 63, rest = g >> 6;
    int i = rest % NKH, h = rest / NKH;
    int s = hh[i];
    float kv = k[(size_t)s * HID + h * HD + d];
    float vv = v[(size_t)s * HID + h * HD + d];
    size_t kd = ((size_t)h * NCATP + i) * HD + d;
    size_t vd = ((size_t)h * HD + d) * NCATP + i;
    short hb = f2bf(kv);
    khi[kd] = (unsigned short)hb;
    klo[kd] = (unsigned short)f2bf(kv - bf2f(hb));
    hb = f2bf(vv);
    vthi[vd] = (unsigned short)hb;
    vtlo[vd] = (unsigned short)f2bf(vv - bf2f(hb));
}

// zero the 52 pad keys per head in all four split arrays
__global__ __launch_bounds__(256) void padzero_k(unsigned short* __restrict__ khi,
                                                 unsigned short* __restrict__ klo,
                                                 unsigned short* __restrict__ vthi,
                                                 unsigned short* __restrict__ vtlo) {
    int g = blockIdx.x * 256 + threadIdx.x;
    if (g >= NH * (NCATP - NCAT) * HD) return;
    int d = g & 63, rest = g >> 6;
    int i = rest % (NCATP - NCAT), h = rest / (NCATP - NCAT);
    size_t kd = ((size_t)h * NCATP + NCAT + i) * HD + d;
    size_t vd = ((size_t)h * HD + d) * NCATP + NCAT + i;
    khi[kd] = 0; klo[kd] = 0;
    vthi[vd] = 0; vtlo[vd] = 0;
}

// ---------------------------------------------------------------------------
// Final attention via bf16x3 MFMA + __expf (round-7 structure, unchanged).
// ---------------------------------------------------------------------------
__global__ __launch_bounds__(256) void attn_mfma(const unsigned short* __restrict__ qhi,
                                                 const unsigned short* __restrict__ qlo,
                                                 const unsigned short* __restrict__ kchi,
                                                 const unsigned short* __restrict__ kclo,
                                                 const unsigned short* __restrict__ vthi,
                                                 const unsigned short* __restrict__ vtlo,
                                                 unsigned short* __restrict__ aohi,
                                                 unsigned short* __restrict__ aolo) {
    __shared__ unsigned short phi[16][776];
    __shared__ unsigned short plo[16][776];
    __shared__ float redm[4][16], redl[4][16];
    int h  = blockIdx.x;
    int m0 = blockIdx.y * 16;
    int t  = threadIdx.x;
    int lane = t & 63, w = t >> 6;
    int quad = lane >> 4, c16 = lane & 15;

    const unsigned short* qph = qhi + ((size_t)h * SEQ + m0 + c16) * HD;
    const unsigned short* qpl = qlo + ((size_t)h * SEQ + m0 + c16) * HD;
    short8 Ah0 = *(const short8*)(qph + quad*8);
    short8 Ah1 = *(const short8*)(qph + 32 + quad*8);
    short8 Al0 = *(const short8*)(qpl + quad*8);
    short8 Al1 = *(const short8*)(qpl + 32 + quad*8);

    float sreg[12][4];
    #pragma unroll
    for (int nt = 0; nt < 12; ++nt) {
        int key = w*192 + nt*16 + c16;
        const unsigned short* kbh = kchi + ((size_t)h * NCATP + key) * HD;
        const unsigned short* kbl = kclo + ((size_t)h * NCATP + key) * HD;
        short8 Bh0 = *(const short8*)(kbh + quad*8);
        short8 Bh1 = *(const short8*)(kbh + 32 + quad*8);
        short8 Bl0 = *(const short8*)(kbl + quad*8);
        short8 Bl1 = *(const short8*)(kbl + 32 + quad*8);
        f32x4 acc = {0.f, 0.f, 0.f, 0.f};
        acc = __builtin_amdgcn_mfma_f32_16x16x32_bf16(Ah0, Bh0, acc, 0, 0, 0);
        acc = __builtin_amdgcn_mfma_f32_16x16x32_bf16(Al0, Bh0, acc, 0, 0, 0);
        acc = __builtin_amdgcn_mfma_f32_16x16x32_bf16(Ah0, Bl0, acc, 0, 0, 0);
        acc = __builtin_amdgcn_mfma_f32_16x16x32_bf16(Ah1, Bh1, acc, 0, 0, 0);
        acc = __builtin_amdgcn_mfma_f32_16x16x32_bf16(Al1, Bh1, acc, 0, 0, 0);
        acc = __builtin_amdgcn_mfma_f32_16x16x32_bf16(Ah1, Bl1, acc, 0, 0, 0);
        bool bad = key >= NCAT;
        #pragma unroll
        for (int i = 0; i < 4; ++i)
            sreg[nt][i] = bad ? -1e30f : acc[i] * SCALE;
    }

    float m[4], l[4];
    #pragma unroll
    for (int i = 0; i < 4; ++i) {
        float mm = -1e30f;
        #pragma unroll
        for (int nt = 0; nt < 12; ++nt) mm = fmaxf(mm, sreg[nt][i]);
        #pragma unroll
        for (int off = 1; off <= 8; off <<= 1) mm = fmaxf(mm, __shfl_xor(mm, off));
        m[i] = mm;
    }
    if (c16 == 0) {
        #pragma unroll
        for (int i = 0; i < 4; ++i) redm[w][quad*4 + i] = m[i];
    }
    __syncthreads();
    #pragma unroll
    for (int i = 0; i < 4; ++i) {
        int row = quad*4 + i;
        m[i] = fmaxf(fmaxf(redm[0][row], redm[1][row]),
                     fmaxf(redm[2][row], redm[3][row]));
    }
    #pragma unroll
    for (int i = 0; i < 4; ++i) {
        float ll = 0.f;
        #pragma unroll
        for (int nt = 0; nt < 12; ++nt) ll += __expf(sreg[nt][i] - m[i]);
        #pragma unroll
        for (int off = 1; off <= 8; off <<= 1) ll += __shfl_xor(ll, off);
        l[i] = ll;
    }
    if (c16 == 0) {
        #pragma unroll
        for (int i = 0; i < 4; ++i) redl[w][quad*4 + i] = l[i];
    }
    __syncthreads();
    float inv[4];
    #pragma unroll
    for (int i = 0; i < 4; ++i) {
        int row = quad*4 + i;
        inv[i] = 1.f / (redl[0][row] + redl[1][row] + redl[2][row] + redl[3][row]);
    }

    #pragma unroll
    for (int nt = 0; nt < 12; ++nt) {
        int key = w*192 + nt*16 + c16;
        #pragma unroll
        for (int i = 0; i < 4; ++i) {
            float p = __expf(sreg[nt][i] - m[i]) * inv[i];
            short ph = f2bf(p);
            phi[quad*4 + i][key] = (unsigned short)ph;
            plo[quad*4 + i][key] = (unsigned short)f2bf(p - bf2f(ph));
        }
    }
    __syncthreads();

    int dim = w*16 + c16;
    const unsigned short* vh = vthi + ((size_t)h * HD + dim) * NCATP;
    const unsigned short* vl = vtlo + ((size_t)h * HD + dim) * NCATP;
    f32x4 ohh = {0.f,0.f,0.f,0.f}, olh = {0.f,0.f,0.f,0.f}, ohl = {0.f,0.f,0.f,0.f};
    #pragma unroll 4
    for (int s = 0; s < 24; ++s) {
        int k0 = s*32 + quad*8;
        short8 Ph = *(const short8*)&phi[c16][k0];
        short8 Pl = *(const short8*)&plo[c16][k0];
        short8 Vh = *(const short8*)(vh + k0);
        short8 Vl = *(const short8*)(vl + k0);
        ohh = __builtin_amdgcn_mfma_f32_16x16x32_bf16(Ph, Vh, ohh, 0, 0, 0);
        olh = __builtin_amdgcn_mfma_f32_16x16x32_bf16(Pl, Vh, olh, 0, 0, 0);
        ohl = __builtin_amdgcn_mfma_f32_16x16x32_bf16(Ph, Vl, ohl, 0, 0, 0);
    }
    #pragma unroll
    for (int i = 0; i < 4; ++i) {
        float val = ohh[i] + olh[i] + ohl[i];
        size_t o = (size_t)(m0 + quad*4 + i) * HID + h * HD + dim;
        short hb = f2bf(val);
        aohi[o] = (unsigned short)hb;
        aolo[o] = (unsigned short)f2bf(val - bf2f(hb));
    }
}

// ---------------------------------------------------------------------------
extern "C" void kernel_launch(void* const* d_in, const int* in_sizes, int n_in,
                              void* d_out, int out_size, void* d_ws, size_t ws_size,
                              hipStream_t stream) {
    const float* x  = (const float*)d_in[0];
    const float* Wq = (const float*)d_in[1];
    const float* Wk = (const float*)d_in[2];
    const float* Wv = (const float*)d_in[3];
    const float* Wo = (const float*)d_in[4];
    float* out = (float*)d_out;

    char* base = (char*)d_ws;                       // 62 MB total
    const size_t MB = 1u << 20;
    float* kf = (float*)(base + 0);                 // 8 MB
    float* vf = (float*)(base + 8*MB);              // 8 MB
    unsigned short* xhi = (unsigned short*)(base + 16*MB);   // 4 MB (-> ao)
    unsigned short* xlo = (unsigned short*)(base + 20*MB);   // 4 MB
    unsigned short* wallhi = (unsigned short*)(base + 24*MB); // 6 MB [Wq|Wk|Wv]
    unsigned short* walllo = (unsigned short*)(base + 30*MB); // 6 MB
    unsigned short* wohi = (unsigned short*)(base + 36*MB);  // 2 MB
    unsigned short* wolo = (unsigned short*)(base + 38*MB);  // 2 MB
    unsigned short* qsphi = (unsigned short*)(base + 40*MB); // 4 MB [h][s][d]
    unsigned short* qsplo = (unsigned short*)(base + 44*MB);
    unsigned short* ksphi = (unsigned short*)(base + 48*MB); // 4 MB [h][s][d]
    unsigned short* ksplo = (unsigned short*)(base + 52*MB);
    // aliases (ordered reuse on the in-order stream):
    unsigned short* aohi = xhi;                     // after gemm_qkv consumed x
    unsigned short* aolo = xlo;
    const size_t CATB = (size_t)NH * NCATP * HD * 2; // 1.5 MB
    unsigned short* kchi = (unsigned short*)(base + 48*MB);  // after score_mfma
    unsigned short* kclo = (unsigned short*)(base + 48*MB + CATB);
    unsigned short* vthi = (unsigned short*)(base + 48*MB + 2*CATB);
    unsigned short* vtlo = (unsigned short*)(base + 48*MB + 3*CATB);
    // small buffers
    char* sm = base + 56*MB;
    float* ent  = (float*)sm;                 sm += NH*SEQ*4;
    float* mxa  = (float*)sm;                 sm += NH*SEQ*4;
    float* imp  = (float*)sm;                 sm += SEQ*4;
    int*   hh   = (int*)sm;                   sm += 256*4;
    float* wk   = (float*)sm;                 sm += NH*SEQ*4;
    float* wv   = (float*)sm;                 sm += NH*SEQ*4;
    float* red  = (float*)sm;                 // 64*SEQ*4 = 512 KB
    __half* part = (__half*)(base + 58*MB);   // 1024*2048*2 = 4 MB

    // 1. split inputs (Wo gets its own slot -> no ordering hack)
    splitx_k<<<SEQ*HID/1024, 256, 0, stream>>>(x, xhi, xlo);
    splitw_k<<<dim3(16,16), 256, 0, stream>>>(Wq, wallhi, walllo);
    splitw_k<<<dim3(16,16), 256, 0, stream>>>(Wk, wallhi + HID*HID, walllo + HID*HID);
    splitw_k<<<dim3(16,16), 256, 0, stream>>>(Wv, wallhi + 2*HID*HID, walllo + 2*HID*HID);
    splitw_k<<<dim3(16,16), 256, 0, stream>>>(Wo, wohi, wolo);

    // 2. fused QKV projection
    gemm_qkv<<<dim3(64,24), 256, 0, stream>>>(xhi, xlo, wallhi, walllo,
                                              qsphi, qsplo, kf, ksphi, ksplo, vf);

    // 3. score stats + heavy hitters
    score_mfma<<<dim3(NH, SEQ/32), 256, 0, stream>>>(qsphi, qsplo, ksphi, ksplo, ent, mxa, part);
    reduce_infl<<<dim3(SEQ/256, 64), 256, 0, stream>>>(part, red);
    importance_k<<<SEQ/256, 256, 0, stream>>>(ent, mxa, red, imp);
    topk_k<<<SEQ/256, 256, 0, stream>>>(imp, hh);

    // 4. compression weights + cat building (cat arrays reuse ksp slot)
    norms_k<<<NH*SEQ/4, 256, 0, stream>>>(kf, wk);
    norms_k<<<NH*SEQ/4, 256, 0, stream>>>(vf, wv);
    softw_k<<<NH, 256, 0, stream>>>(wk);
    softw_k<<<NH, 256, 0, stream>>>(wv);
    poolk_k<<<NH*LCOMP*HD/256, 256, 0, stream>>>(kf, wk, kchi, kclo);
    poolv_k<<<NH*LCOMP*HD/256, 256, 0, stream>>>(vf, wv, vthi, vtlo);
    padzero_k<<<208, 256, 0, stream>>>(kchi, kclo, vthi, vtlo);
    gather_k<<<NH*NKH*HD/256, 256, 0, stream>>>(kf, vf, hh, kchi, kclo, vthi, vtlo);

    // 5. final attention (writes pre-split ao into x slot)
    attn_mfma<<<dim3(NH, SEQ/16), 256, 0, stream>>>(qsphi, qsplo, kchi, kclo, vthi, vtlo, aohi, aolo);

    // 6. output projection
    gemm_sp<<<dim3(64,8), 256, 0, stream>>>(aohi, aolo, wohi, wolo, out);
}

// Round 9
// 494.725 us; speedup vs baseline: 1.6836x; 1.3282x over previous
//
#include <hip/hip_runtime.h>
#include <hip/hip_fp16.h>
#include <math.h>

#define SEQ   2048
#define HID   1024
#define NH    16
#define HD    64
#define NKH   204          // heavy hitters = int(2048*0.1)
#define LCOMP 512          // compressed length = 2048/4
#define NCAT  716          // 204 + 512
#define NCATP 768          // padded to multiple of 64 (52 pad keys)
#define SCALE 0.125f       // 1/sqrt(64)

typedef __attribute__((ext_vector_type(8))) short short8;   // 8 bf16 (4 VGPRs)
typedef __attribute__((ext_vector_type(4))) float f32x4;    // MFMA accumulator

// ---- bf16 split helpers (RNE) -------------------------------------------
__device__ __forceinline__ short f2bf(float f) {
    unsigned u = __builtin_bit_cast(unsigned, f);
    u += 0x7FFFu + ((u >> 16) & 1u);
    return (short)(u >> 16);
}
__device__ __forceinline__ float bf2f(short h) {
    unsigned u = ((unsigned)(unsigned short)h) << 16;
    return __builtin_bit_cast(float, u);
}

// ---------------------------------------------------------------------------
// One-pass splitters: f32 -> bf16 hi/lo.
// ---------------------------------------------------------------------------
__global__ __launch_bounds__(256) void splitx_k(const float* __restrict__ X,
                                                unsigned short* __restrict__ hi,
                                                unsigned short* __restrict__ lo) {
    size_t g = ((size_t)blockIdx.x * 256 + threadIdx.x) * 4;
    float4 v4 = *(const float4*)(X + g);
    ushort4 h4, l4;
    short hb;
    hb = f2bf(v4.x); h4.x = hb; l4.x = (unsigned short)f2bf(v4.x - bf2f(hb));
    hb = f2bf(v4.y); h4.y = hb; l4.y = (unsigned short)f2bf(v4.y - bf2f(hb));
    hb = f2bf(v4.z); h4.z = hb; l4.z = (unsigned short)f2bf(v4.z - bf2f(hb));
    hb = f2bf(v4.w); h4.w = hb; l4.w = (unsigned short)f2bf(v4.w - bf2f(hb));
    *(ushort4*)(hi + g) = h4;
    *(ushort4*)(lo + g) = l4;
}

__global__ __launch_bounds__(256) void splitw_k(const float* __restrict__ W,
                                                unsigned short* __restrict__ hi,
                                                unsigned short* __restrict__ lo) {
    __shared__ float tile[64][65];
    int n0 = blockIdx.x * 64, k0 = blockIdx.y * 64;
    int t = threadIdx.x;
    int r = t >> 4, c4 = (t & 15) * 4;
    #pragma unroll
    for (int i = 0; i < 4; ++i) {
        float4 v4 = *(const float4*)(W + (size_t)(k0 + i*16 + r) * HID + n0 + c4);
        tile[i*16 + r][c4+0] = v4.x; tile[i*16 + r][c4+1] = v4.y;
        tile[i*16 + r][c4+2] = v4.z; tile[i*16 + r][c4+3] = v4.w;
    }
    __syncthreads();
    #pragma unroll
    for (int i = 0; i < 4; ++i) {
        int n = i*16 + r;
        float v0 = tile[c4+0][n], v1 = tile[c4+1][n];
        float v2 = tile[c4+2][n], v3 = tile[c4+3][n];
        ushort4 h4, l4;
        short hb;
        hb = f2bf(v0); h4.x = hb; l4.x = (unsigned short)f2bf(v0 - bf2f(hb));
        hb = f2bf(v1); h4.y = hb; l4.y = (unsigned short)f2bf(v1 - bf2f(hb));
        hb = f2bf(v2); h4.z = hb; l4.z = (unsigned short)f2bf(v2 - bf2f(hb));
        hb = f2bf(v3); h4.w = hb; l4.w = (unsigned short)f2bf(v3 - bf2f(hb));
        size_t o = (size_t)(n0 + n) * HID + k0 + c4;
        *(ushort4*)(hi + o) = h4;
        *(ushort4*)(lo + o) = l4;
    }
}

// ---------------------------------------------------------------------------
// LDS-staged bf16x3 MFMA GEMM (m93-style).  Block = BM x BN, BK=32, 4 waves,
// wave = (BM/2)m x (BN/2)n.  A[m][k], B^T[n][k] pre-split; all 4 waves share
// staged tiles.  MODE 1 = fused QKV epilogue (seg = n>>10), MODE 0 = f32 C.
// Per-chunk MFMA order (hh,lh,hl per tile, kt ascending) is identical to the
// round-8 kernels -> bitwise-identical accumulation.
// ---------------------------------------------------------------------------
template<int BM, int BN, int MODE>
__global__ __launch_bounds__(256) void gemm_lds(const unsigned short* __restrict__ Ahi,
                                                const unsigned short* __restrict__ Alo,
                                                const unsigned short* __restrict__ Bthi,
                                                const unsigned short* __restrict__ Btlo,
                                                unsigned short* __restrict__ qhi,
                                                unsigned short* __restrict__ qlo,
                                                float* __restrict__ kf,
                                                unsigned short* __restrict__ khi,
                                                unsigned short* __restrict__ klo,
                                                float* __restrict__ vf,
                                                float* __restrict__ Cf) {
    constexpr int WM = BM / 2, WN = BN / 2;
    constexpr int MT = WM / 16, NT = WN / 16;
    __shared__ __align__(16) unsigned short Ah_s[BM * 32];
    __shared__ __align__(16) unsigned short Al_s[BM * 32];
    __shared__ __align__(16) unsigned short Bh_s[BN * 32];
    __shared__ __align__(16) unsigned short Bl_s[BN * 32];
    int t = threadIdx.x, lane = t & 63, w = t >> 6;
    int quad = lane >> 4, c16 = lane & 15;
    int m0 = blockIdx.x * BM, n0 = blockIdx.y * BN;
    int moff = (w & 1) * WM, noff = (w >> 1) * WN;
    int sr = t >> 2, skq = (t & 3) * 8;          // staging: row, k-offset

    f32x4 acc[MT][NT];
    #pragma unroll
    for (int mt = 0; mt < MT; ++mt)
        #pragma unroll
        for (int nt = 0; nt < NT; ++nt)
            acc[mt][nt] = (f32x4){0.f, 0.f, 0.f, 0.f};

    for (int kt = 0; kt < HID; kt += 32) {
        __syncthreads();
        #pragma unroll
        for (int p = 0; p < BM / 64; ++p) {
            int row = p * 64 + sr;
            *(short8*)&Ah_s[row * 32 + skq] =
                *(const short8*)(Ahi + (size_t)(m0 + row) * HID + kt + skq);
            *(short8*)&Al_s[row * 32 + skq] =
                *(const short8*)(Alo + (size_t)(m0 + row) * HID + kt + skq);
        }
        #pragma unroll
        for (int p = 0; p < BN / 64; ++p) {
            int row = p * 64 + sr;
            *(short8*)&Bh_s[row * 32 + skq] =
                *(const short8*)(Bthi + (size_t)(n0 + row) * HID + kt + skq);
            *(short8*)&Bl_s[row * 32 + skq] =
                *(const short8*)(Btlo + (size_t)(n0 + row) * HID + kt + skq);
        }
        __syncthreads();
        short8 Bh[NT], Bl[NT];
        #pragma unroll
        for (int nt = 0; nt < NT; ++nt) {
            int row = noff + nt * 16 + c16;
            Bh[nt] = *(const short8*)&Bh_s[row * 32 + quad * 8];
            Bl[nt] = *(const short8*)&Bl_s[row * 32 + quad * 8];
        }
        #pragma unroll
        for (int mt = 0; mt < MT; ++mt) {
            int row = moff + mt * 16 + c16;
            short8 Ah = *(const short8*)&Ah_s[row * 32 + quad * 8];
            short8 Al = *(const short8*)&Al_s[row * 32 + quad * 8];
            #pragma unroll
            for (int nt = 0; nt < NT; ++nt) {
                acc[mt][nt] = __builtin_amdgcn_mfma_f32_16x16x32_bf16(Ah, Bh[nt], acc[mt][nt], 0, 0, 0);
                acc[mt][nt] = __builtin_amdgcn_mfma_f32_16x16x32_bf16(Al, Bh[nt], acc[mt][nt], 0, 0, 0);
                acc[mt][nt] = __builtin_amdgcn_mfma_f32_16x16x32_bf16(Ah, Bl[nt], acc[mt][nt], 0, 0, 0);
            }
        }
    }

    #pragma unroll
    for (int mt = 0; mt < MT; ++mt)
    #pragma unroll
    for (int nt = 0; nt < NT; ++nt)
    #pragma unroll
    for (int i = 0; i < 4; ++i) {
        int m  = m0 + moff + mt * 16 + quad * 4 + i;
        int ng = n0 + noff + nt * 16 + c16;
        float val = acc[mt][nt][i];
        if (MODE == 1) {
            int seg = ng >> 10;            // 0=q, 1=k, 2=v
            int nl  = ng & 1023;
            if (seg == 0) {
                size_t o = ((size_t)(nl >> 6) * SEQ + m) * HD + (nl & 63);
                short hb = f2bf(val);
                qhi[o] = (unsigned short)hb;
                qlo[o] = (unsigned short)f2bf(val - bf2f(hb));
            } else if (seg == 1) {
                kf[(size_t)m * HID + nl] = val;
                size_t o = ((size_t)(nl >> 6) * SEQ + m) * HD + (nl & 63);
                short hb = f2bf(val);
                khi[o] = (unsigned short)hb;
                klo[o] = (unsigned short)f2bf(val - bf2f(hb));
            } else {
                vf[(size_t)m * HID + nl] = val;
            }
        } else {
            Cf[(size_t)m * HID + ng] = val;
        }
    }
}

// ---------------------------------------------------------------------------
// Score stats v4: two-pass recompute, NO score storage (VGPR-light).
// Block = (head, 32 q rows), wave w owns keys [w*512,+512).
// ---------------------------------------------------------------------------
__global__ __launch_bounds__(256) void score_mfma(const unsigned short* __restrict__ qhi,
                                                  const unsigned short* __restrict__ qlo,
                                                  const unsigned short* __restrict__ khi,
                                                  const unsigned short* __restrict__ klo,
                                                  float* __restrict__ ent,
                                                  float* __restrict__ mxa,
                                                  __half* __restrict__ part) {
    __shared__ float redm[4][32], redl[4][32], rede[4][32];
    int h  = blockIdx.x;
    int qb = blockIdx.y;
    int m0 = qb * 32;
    int t  = threadIdx.x;
    int lane = t & 63, w = t >> 6;
    int quad = lane >> 4, c16 = lane & 15;

    short8 Ah0[2], Ah1[2], Al0[2], Al1[2];
    #pragma unroll
    for (int rt = 0; rt < 2; ++rt) {
        const unsigned short* qph = qhi + ((size_t)h * SEQ + m0 + rt*16 + c16) * HD;
        const unsigned short* qpl = qlo + ((size_t)h * SEQ + m0 + rt*16 + c16) * HD;
        Ah0[rt] = *(const short8*)(qph + quad*8);
        Ah1[rt] = *(const short8*)(qph + 32 + quad*8);
        Al0[rt] = *(const short8*)(qpl + quad*8);
        Al1[rt] = *(const short8*)(qpl + 32 + quad*8);
    }

    float l[2][4] = {}, ee[2][4] = {};
    float mx[2][4] = {{-1e30f,-1e30f,-1e30f,-1e30f},{-1e30f,-1e30f,-1e30f,-1e30f}};
    #pragma unroll
    for (int nt = 0; nt < 32; ++nt) {
        int key = (w * 32 + nt) * 16 + c16;
        const unsigned short* kbh = khi + ((size_t)h * SEQ + key) * HD;
        const unsigned short* kbl = klo + ((size_t)h * SEQ + key) * HD;
        short8 Bh0 = *(const short8*)(kbh + quad*8);
        short8 Bh1 = *(const short8*)(kbh + 32 + quad*8);
        short8 Bl0 = *(const short8*)(kbl + quad*8);
        short8 Bl1 = *(const short8*)(kbl + 32 + quad*8);
        #pragma unroll
        for (int rt = 0; rt < 2; ++rt) {
            f32x4 acc = {0.f, 0.f, 0.f, 0.f};
            acc = __builtin_amdgcn_mfma_f32_16x16x32_bf16(Ah0[rt], Bh0, acc, 0, 0, 0);
            acc = __builtin_amdgcn_mfma_f32_16x16x32_bf16(Al0[rt], Bh0, acc, 0, 0, 0);
            acc = __builtin_amdgcn_mfma_f32_16x16x32_bf16(Ah0[rt], Bl0, acc, 0, 0, 0);
            acc = __builtin_amdgcn_mfma_f32_16x16x32_bf16(Ah1[rt], Bh1, acc, 0, 0, 0);
            acc = __builtin_amdgcn_mfma_f32_16x16x32_bf16(Al1[rt], Bh1, acc, 0, 0, 0);
            acc = __builtin_amdgcn_mfma_f32_16x16x32_bf16(Ah1[rt], Bl1, acc, 0, 0, 0);
            #pragma unroll
            for (int i = 0; i < 4; ++i) {
                float s = acc[i] * SCALE;
                float tt = __expf(s);          // safe: |s| << 88
                l[rt][i] += tt;
                ee[rt][i] += tt * s;
                mx[rt][i] = fmaxf(mx[rt][i], s);
            }
        }
    }
    #pragma unroll
    for (int rt = 0; rt < 2; ++rt)
    #pragma unroll
    for (int i = 0; i < 4; ++i) {
        #pragma unroll
        for (int off = 1; off <= 8; off <<= 1) {
            l[rt][i]  += __shfl_xor(l[rt][i], off);
            ee[rt][i] += __shfl_xor(ee[rt][i], off);
            mx[rt][i]  = fmaxf(mx[rt][i], __shfl_xor(mx[rt][i], off));
        }
    }
    if (c16 == 0) {
        #pragma unroll
        for (int rt = 0; rt < 2; ++rt)
        #pragma unroll
        for (int i = 0; i < 4; ++i) {
            int row = rt*16 + quad*4 + i;
            redl[w][row] = l[rt][i];
            rede[w][row] = ee[rt][i];
            redm[w][row] = mx[rt][i];
        }
    }
    __syncthreads();
    float inv[2][4];
    #pragma unroll
    for (int rt = 0; rt < 2; ++rt)
    #pragma unroll
    for (int i = 0; i < 4; ++i) {
        int row = rt*16 + quad*4 + i;
        float lf = redl[0][row] + redl[1][row] + redl[2][row] + redl[3][row];
        inv[rt][i] = 1.f / lf;
        if (w == 0 && c16 == 0) {
            float eef = rede[0][row] + rede[1][row] + rede[2][row] + rede[3][row];
            float mf  = fmaxf(fmaxf(redm[0][row], redm[1][row]),
                              fmaxf(redm[2][row], redm[3][row]));
            mxa[h*SEQ + m0 + row] = __expf(mf) * inv[rt][i];
            ent[h*SEQ + m0 + row] = __logf(lf) - eef * inv[rt][i];
        }
    }

    __half* pslab = part + (size_t)(h * (SEQ/32) + qb) * SEQ;
    #pragma unroll
    for (int nt = 0; nt < 32; ++nt) {
        int key = (w * 32 + nt) * 16 + c16;
        const unsigned short* kbh = khi + ((size_t)h * SEQ + key) * HD;
        const unsigned short* kbl = klo + ((size_t)h * SEQ + key) * HD;
        short8 Bh0 = *(const short8*)(kbh + quad*8);
        short8 Bh1 = *(const short8*)(kbh + 32 + quad*8);
        short8 Bl0 = *(const short8*)(kbl + quad*8);
        short8 Bl1 = *(const short8*)(kbl + 32 + quad*8);
        float cs = 0.f;
        #pragma unroll
        for (int rt = 0; rt < 2; ++rt) {
            f32x4 acc = {0.f, 0.f, 0.f, 0.f};
            acc = __builtin_amdgcn_mfma_f32_16x16x32_bf16(Ah0[rt], Bh0, acc, 0, 0, 0);
            acc = __builtin_amdgcn_mfma_f32_16x16x32_bf16(Al0[rt], Bh0, acc, 0, 0, 0);
            acc = __builtin_amdgcn_mfma_f32_16x16x32_bf16(Ah0[rt], Bl0, acc, 0, 0, 0);
            acc = __builtin_amdgcn_mfma_f32_16x16x32_bf16(Ah1[rt], Bh1, acc, 0, 0, 0);
            acc = __builtin_amdgcn_mfma_f32_16x16x32_bf16(Al1[rt], Bh1, acc, 0, 0, 0);
            acc = __builtin_amdgcn_mfma_f32_16x16x32_bf16(Ah1[rt], Bl1, acc, 0, 0, 0);
            #pragma unroll
            for (int i = 0; i < 4; ++i)
                cs += __expf(acc[i] * SCALE) * inv[rt][i];
        }
        cs += __shfl_xor(cs, 16);
        cs += __shfl_xor(cs, 32);
        if (lane < 16) pslab[(w*32 + nt)*16 + lane] = __float2half(cs);
    }
}

// stage-1 influence reduction: red[g][s] = sum of 16 slabs (f16 -> f32)
__global__ __launch_bounds__(256) void reduce_infl(const __half* __restrict__ part,
                                                   float* __restrict__ red) {
    int s = blockIdx.x * 256 + threadIdx.x;
    int g = blockIdx.y;
    const __half* p = part + (size_t)g * 16 * SEQ + s;
    float a = 0.f;
    #pragma unroll
    for (int i = 0; i < 16; ++i) a += __half2float(p[(size_t)i * SEQ]);
    red[(size_t)g * SEQ + s] = a;
}

__global__ __launch_bounds__(256) void importance_k(const float* __restrict__ ent,
                                                    const float* __restrict__ mxa,
                                                    const float* __restrict__ red,
                                                    float* __restrict__ imp) {
    int s = blockIdx.x * 256 + threadIdx.x;
    float es = 0.f, ms = 0.f;
    #pragma unroll
    for (int h = 0; h < NH; ++h) { es += ent[h*SEQ + s]; ms += mxa[h*SEQ + s]; }
    float inf = 0.f;
    #pragma unroll 8
    for (int g = 0; g < 64; ++g) inf += red[(size_t)g * SEQ + s];
    imp[s] = (-0.4f*es + 0.3f*ms + 0.3f*inf) * (1.f/16.f);
}

// Deterministic top-k by rank counting (matches lax.top_k set semantics).
__global__ __launch_bounds__(256) void topk_k(const float* __restrict__ imp,
                                              int* __restrict__ hh) {
    __shared__ float si[SEQ];
    int t = threadIdx.x, s = blockIdx.x * 256 + t;
    for (int i = t; i < SEQ; i += 256) si[i] = imp[i];
    __syncthreads();
    float v = si[s];
    int rank = 0;
    #pragma unroll 1
    for (int i = 0; i < SEQ; ++i) {
        float u = si[i];
        rank += (u > v) || (u == v && i < s);
    }
    if (rank < NKH) hh[rank] = s;
}

// per-(h,s) L2 norm of a 64-dim head vector (one wave each)
__global__ __launch_bounds__(256) void norms_k(const float* __restrict__ x,
                                               float* __restrict__ n) {
    int t = threadIdx.x;
    int wid = blockIdx.x * 4 + (t >> 6);
    int lane = t & 63;
    int h = wid >> 11, s = wid & 2047;
    float v = x[(size_t)s * HID + h * HD + lane];
    float ss = v * v;
    #pragma unroll
    for (int off = 32; off; off >>= 1) ss += __shfl_xor(ss, off);
    if (lane == 0) n[h*SEQ + s] = sqrtf(ss);
}

// in-place softmax over SEQ per head (one block per head)
__global__ __launch_bounds__(256) void softw_k(float* __restrict__ n) {
    __shared__ float red[8];
    int h = blockIdx.x, t = threadIdx.x, lane = t & 63, w = t >> 6;
    float* nh = n + (size_t)h * SEQ;
    float m = -1e30f;
    for (int i = t; i < SEQ; i += 256) m = fmaxf(m, nh[i]);
    #pragma unroll
    for (int off = 32; off; off >>= 1) m = fmaxf(m, __shfl_xor(m, off));
    if (lane == 0) red[w] = m;
    __syncthreads();
    m = fmaxf(fmaxf(red[0], red[1]), fmaxf(red[2], red[3]));
    float z = 0.f;
    for (int i = t; i < SEQ; i += 256) z += __expf(nh[i] - m);
    #pragma unroll
    for (int off = 32; off; off >>= 1) z += __shfl_xor(z, off);
    if (lane == 0) red[4 + w] = z;
    __syncthreads();
    z = red[4] + red[5] + red[6] + red[7];
    for (int i = t; i < SEQ; i += 256) nh[i] = __expf(nh[i] - m) / z;
}

// group-4 weighted pooling of K -> pre-split bf16 [h][key][d]
__global__ __launch_bounds__(256) void poolk_k(const float* __restrict__ src,
                                               const float* __restrict__ w,
                                               unsigned short* __restrict__ hi,
                                               unsigned short* __restrict__ lo) {
    int g = blockIdx.x * 256 + threadIdx.x;
    int d = g & 63, rest = g >> 6;
    int l = rest & 511, h = rest >> 9;
    const float* wp = w + (size_t)h * SEQ + l * 4;
    float w0 = wp[0], w1 = wp[1], w2 = wp[2], w3 = wp[3];
    float wsum = w0 + w1 + w2 + w3 + 1e-8f;
    size_t base = (size_t)(l*4) * HID + h * HD + d;
    float val = (src[base]*w0 + src[base+HID]*w1 + src[base+2*HID]*w2 + src[base+3*HID]*w3) / wsum;
    size_t dst = ((size_t)h * NCATP + NKH + l) * HD + d;
    short hb = f2bf(val);
    hi[dst] = (unsigned short)hb;
    lo[dst] = (unsigned short)f2bf(val - bf2f(hb));
}

// group-4 weighted pooling of V -> pre-split bf16 TRANSPOSED [h][d][key]
__global__ __launch_bounds__(256) void poolv_k(const float* __restrict__ src,
                                               const float* __restrict__ w,
                                               unsigned short* __restrict__ hi,
                                               unsigned short* __restrict__ lo) {
    int g = blockIdx.x * 256 + threadIdx.x;
    int d = g & 63, rest = g >> 6;
    int l = rest & 511, h = rest >> 9;
    const float* wp = w + (size_t)h * SEQ + l * 4;
    float w0 = wp[0], w1 = wp[1], w2 = wp[2], w3 = wp[3];
    float wsum = w0 + w1 + w2 + w3 + 1e-8f;
    size_t base = (size_t)(l*4) * HID + h * HD + d;
    float val = (src[base]*w0 + src[base+HID]*w1 + src[base+2*HID]*w2 + src[base+3*HID]*w3) / wsum;
    size_t dst = ((size_t)h * HD + d) * NCATP + NKH + l;
    short hb = f2bf(val);
    hi[dst] = (unsigned short)hb;
    lo[dst] = (unsigned short)f2bf(val - bf2f(hb));
}

// gather heavy-hitter k/v rows -> pre-split bf16 (K direct, V transposed)
__global__ __launch_bounds__(256) void gather_k(const float* __restrict__ k,
                                                const float* __restrict__ v,
                                                const int* __restrict__ hh,
                                                unsigned short* __restrict__ khi,
                                                unsigned short* __restrict__ klo,
                                                unsigned short* __restrict__ vthi,
                                                unsigned short* __restrict__ vtlo) {
    int g = blockIdx.x * 256 + threadIdx.x;
    int d = g & 63, rest = g >> 6;
    int i = rest % NKH, h = rest / NKH;
    int s = hh[i];
    float kv = k[(size_t)s * HID + h * HD + d];
    float vv = v[(size_t)s * HID + h * HD + d];
    size_t kd = ((size_t)h * NCATP + i) * HD + d;
    size_t vd = ((size_t)h * HD + d) * NCATP + i;
    short hb = f2bf(kv);
    khi[kd] = (unsigned short)hb;
    klo[kd] = (unsigned short)f2bf(kv - bf2f(hb));
    hb = f2bf(vv);
    vthi[vd] = (unsigned short)hb;
    vtlo[vd] = (unsigned short)f2bf(vv - bf2f(hb));
}

// zero the 52 pad keys per head in all four split arrays
__global__ __launch_bounds__(256) void padzero_k(unsigned short* __restrict__ khi,
                                                 unsigned short* __restrict__ klo,
                                                 unsigned short* __restrict__ vthi,
                                                 unsigned short* __restrict__ vtlo) {
    int g = blockIdx.x * 256 + threadIdx.x;
    if (g >= NH * (NCATP - NCAT) * HD) return;
    int d = g & 63, rest = g >> 6;
    int i = rest % (NCATP - NCAT), h = rest / (NCATP - NCAT);
    size_t kd = ((size_t)h * NCATP + NCAT + i) * HD + d;
    size_t vd = ((size_t)h * HD + d) * NCATP + NCAT + i;
    khi[kd] = 0; klo[kd] = 0;
    vthi[vd] = 0; vtlo[vd] = 0;
}

// ---------------------------------------------------------------------------
// Final attention via bf16x3 MFMA + __expf (unchanged).
// ---------------------------------------------------------------------------
__global__ __launch_bounds__(256) void attn_mfma(const unsigned short* __restrict__ qhi,
                                                 const unsigned short* __restrict__ qlo,
                                                 const unsigned short* __restrict__ kchi,
                                                 const unsigned short* __restrict__ kclo,
                                                 const unsigned short* __restrict__ vthi,
                                                 const unsigned short* __restrict__ vtlo,
                                                 unsigned short* __restrict__ aohi,
                                                 unsigned short* __restrict__ aolo) {
    __shared__ unsigned short phi[16][776];
    __shared__ unsigned short plo[16][776];
    __shared__ float redm[4][16], redl[4][16];
    int h  = blockIdx.x;
    int m0 = blockIdx.y * 16;
    int t  = threadIdx.x;
    int lane = t & 63, w = t >> 6;
    int quad = lane >> 4, c16 = lane & 15;

    const unsigned short* qph = qhi + ((size_t)h * SEQ + m0 + c16) * HD;
    const unsigned short* qpl = qlo + ((size_t)h * SEQ + m0 + c16) * HD;
    short8 Ah0 = *(const short8*)(qph + quad*8);
    short8 Ah1 = *(const short8*)(qph + 32 + quad*8);
    short8 Al0 = *(const short8*)(qpl + quad*8);
    short8 Al1 = *(const short8*)(qpl + 32 + quad*8);

    float sreg[12][4];
    #pragma unroll
    for (int nt = 0; nt < 12; ++nt) {
        int key = w*192 + nt*16 + c16;
        const unsigned short* kbh = kchi + ((size_t)h * NCATP + key) * HD;
        const unsigned short* kbl = kclo + ((size_t)h * NCATP + key) * HD;
        short8 Bh0 = *(const short8*)(kbh + quad*8);
        short8 Bh1 = *(const short8*)(kbh + 32 + quad*8);
        short8 Bl0 = *(const short8*)(kbl + quad*8);
        short8 Bl1 = *(const short8*)(kbl + 32 + quad*8);
        f32x4 acc = {0.f, 0.f, 0.f, 0.f};
        acc = __builtin_amdgcn_mfma_f32_16x16x32_bf16(Ah0, Bh0, acc, 0, 0, 0);
        acc = __builtin_amdgcn_mfma_f32_16x16x32_bf16(Al0, Bh0, acc, 0, 0, 0);
        acc = __builtin_amdgcn_mfma_f32_16x16x32_bf16(Ah0, Bl0, acc, 0, 0, 0);
        acc = __builtin_amdgcn_mfma_f32_16x16x32_bf16(Ah1, Bh1, acc, 0, 0, 0);
        acc = __builtin_amdgcn_mfma_f32_16x16x32_bf16(Al1, Bh1, acc, 0, 0, 0);
        acc = __builtin_amdgcn_mfma_f32_16x16x32_bf16(Ah1, Bl1, acc, 0, 0, 0);
        bool bad = key >= NCAT;
        #pragma unroll
        for (int i = 0; i < 4; ++i)
            sreg[nt][i] = bad ? -1e30f : acc[i] * SCALE;
    }

    float m[4], l[4];
    #pragma unroll
    for (int i = 0; i < 4; ++i) {
        float mm = -1e30f;
        #pragma unroll
        for (int nt = 0; nt < 12; ++nt) mm = fmaxf(mm, sreg[nt][i]);
        #pragma unroll
        for (int off = 1; off <= 8; off <<= 1) mm = fmaxf(mm, __shfl_xor(mm, off));
        m[i] = mm;
    }
    if (c16 == 0) {
        #pragma unroll
        for (int i = 0; i < 4; ++i) redm[w][quad*4 + i] = m[i];
    }
    __syncthreads();
    #pragma unroll
    for (int i = 0; i < 4; ++i) {
        int row = quad*4 + i;
        m[i] = fmaxf(fmaxf(redm[0][row], redm[1][row]),
                     fmaxf(redm[2][row], redm[3][row]));
    }
    #pragma unroll
    for (int i = 0; i < 4; ++i) {
        float ll = 0.f;
        #pragma unroll
        for (int nt = 0; nt < 12; ++nt) ll += __expf(sreg[nt][i] - m[i]);
        #pragma unroll
        for (int off = 1; off <= 8; off <<= 1) ll += __shfl_xor(ll, off);
        l[i] = ll;
    }
    if (c16 == 0) {
        #pragma unroll
        for (int i = 0; i < 4; ++i) redl[w][quad*4 + i] = l[i];
    }
    __syncthreads();
    float inv[4];
    #pragma unroll
    for (int i = 0; i < 4; ++i) {
        int row = quad*4 + i;
        inv[i] = 1.f / (redl[0][row] + redl[1][row] + redl[2][row] + redl[3][row]);
    }

    #pragma unroll
    for (int nt = 0; nt < 12; ++nt) {
        int key = w*192 + nt*16 + c16;
        #pragma unroll
        for (int i = 0; i < 4; ++i) {
            float p = __expf(sreg[nt][i] - m[i]) * inv[i];
            short ph = f2bf(p);
            phi[quad*4 + i][key] = (unsigned short)ph;
            plo[quad*4 + i][key] = (unsigned short)f2bf(p - bf2f(ph));
        }
    }
    __syncthreads();

    int dim = w*16 + c16;
    const unsigned short* vh = vthi + ((size_t)h * HD + dim) * NCATP;
    const unsigned short* vl = vtlo + ((size_t)h * HD + dim) * NCATP;
    f32x4 ohh = {0.f,0.f,0.f,0.f}, olh = {0.f,0.f,0.f,0.f}, ohl = {0.f,0.f,0.f,0.f};
    #pragma unroll 4
    for (int s = 0; s < 24; ++s) {
        int k0 = s*32 + quad*8;
        short8 Ph = *(const short8*)&phi[c16][k0];
        short8 Pl = *(const short8*)&plo[c16][k0];
        short8 Vh = *(const short8*)(vh + k0);
        short8 Vl = *(const short8*)(vl + k0);
        ohh = __builtin_amdgcn_mfma_f32_16x16x32_bf16(Ph, Vh, ohh, 0, 0, 0);
        olh = __builtin_amdgcn_mfma_f32_16x16x32_bf16(Pl, Vh, olh, 0, 0, 0);
        ohl = __builtin_amdgcn_mfma_f32_16x16x32_bf16(Ph, Vl, ohl, 0, 0, 0);
    }
    #pragma unroll
    for (int i = 0; i < 4; ++i) {
        float val = ohh[i] + olh[i] + ohl[i];
        size_t o = (size_t)(m0 + quad*4 + i) * HID + h * HD + dim;
        short hb = f2bf(val);
        aohi[o] = (unsigned short)hb;
        aolo[o] = (unsigned short)f2bf(val - bf2f(hb));
    }
}

// ---------------------------------------------------------------------------
extern "C" void kernel_launch(void* const* d_in, const int* in_sizes, int n_in,
                              void* d_out, int out_size, void* d_ws, size_t ws_size,
                              hipStream_t stream) {
    const float* x  = (const float*)d_in[0];
    const float* Wq = (const float*)d_in[1];
    const float* Wk = (const float*)d_in[2];
    const float* Wv = (const float*)d_in[3];
    const float* Wo = (const float*)d_in[4];
    float* out = (float*)d_out;

    char* base = (char*)d_ws;                       // 62 MB total
    const size_t MB = 1u << 20;
    float* kf = (float*)(base + 0);                 // 8 MB
    float* vf = (float*)(base + 8*MB);              // 8 MB
    unsigned short* xhi = (unsigned short*)(base + 16*MB);   // 4 MB (-> ao)
    unsigned short* xlo = (unsigned short*)(base + 20*MB);   // 4 MB
    unsigned short* wallhi = (unsigned short*)(base + 24*MB); // 6 MB [Wq|Wk|Wv]
    unsigned short* walllo = (unsigned short*)(base + 30*MB); // 6 MB
    unsigned short* wohi = (unsigned short*)(base + 36*MB);  // 2 MB
    unsigned short* wolo = (unsigned short*)(base + 38*MB);  // 2 MB
    unsigned short* qsphi = (unsigned short*)(base + 40*MB); // 4 MB [h][s][d]
    unsigned short* qsplo = (unsigned short*)(base + 44*MB);
    unsigned short* ksphi = (unsigned short*)(base + 48*MB); // 4 MB [h][s][d]
    unsigned short* ksplo = (unsigned short*)(base + 52*MB);
    // aliases (ordered reuse on the in-order stream):
    unsigned short* aohi = xhi;                     // after gemm_qkv consumed x
    unsigned short* aolo = xlo;
    const size_t CATB = (size_t)NH * NCATP * HD * 2; // 1.5 MB
    unsigned short* kchi = (unsigned short*)(base + 48*MB);  // after score_mfma
    unsigned short* kclo = (unsigned short*)(base + 48*MB + CATB);
    unsigned short* vthi = (unsigned short*)(base + 48*MB + 2*CATB);
    unsigned short* vtlo = (unsigned short*)(base + 48*MB + 3*CATB);
    // small buffers
    char* sm = base + 56*MB;
    float* ent  = (float*)sm;                 sm += NH*SEQ*4;
    float* mxa  = (float*)sm;                 sm += NH*SEQ*4;
    float* imp  = (float*)sm;                 sm += SEQ*4;
    int*   hh   = (int*)sm;                   sm += 256*4;
    float* wk   = (float*)sm;                 sm += NH*SEQ*4;
    float* wv   = (float*)sm;                 sm += NH*SEQ*4;
    float* red  = (float*)sm;                 // 64*SEQ*4 = 512 KB
    __half* part = (__half*)(base + 58*MB);   // 1024*2048*2 = 4 MB

    // 1. split inputs
    splitx_k<<<SEQ*HID/1024, 256, 0, stream>>>(x, xhi, xlo);
    splitw_k<<<dim3(16,16), 256, 0, stream>>>(Wq, wallhi, walllo);
    splitw_k<<<dim3(16,16), 256, 0, stream>>>(Wk, wallhi + HID*HID, walllo + HID*HID);
    splitw_k<<<dim3(16,16), 256, 0, stream>>>(Wv, wallhi + 2*HID*HID, walllo + 2*HID*HID);
    splitw_k<<<dim3(16,16), 256, 0, stream>>>(Wo, wohi, wolo);

    // 2. fused QKV projection (LDS-staged)
    gemm_lds<128, 64, 1><<<dim3(16, 48), 256, 0, stream>>>(
        xhi, xlo, wallhi, walllo, qsphi, qsplo, kf, ksphi, ksplo, vf, nullptr);

    // 3. score stats + heavy hitters
    score_mfma<<<dim3(NH, SEQ/32), 256, 0, stream>>>(qsphi, qsplo, ksphi, ksplo, ent, mxa, part);
    reduce_infl<<<dim3(SEQ/256, 64), 256, 0, stream>>>(part, red);
    importance_k<<<SEQ/256, 256, 0, stream>>>(ent, mxa, red, imp);
    topk_k<<<SEQ/256, 256, 0, stream>>>(imp, hh);

    // 4. compression weights + cat building (cat arrays reuse ksp slot)
    norms_k<<<NH*SEQ/4, 256, 0, stream>>>(kf, wk);
    norms_k<<<NH*SEQ/4, 256, 0, stream>>>(vf, wv);
    softw_k<<<NH, 256, 0, stream>>>(wk);
    softw_k<<<NH, 256, 0, stream>>>(wv);
    poolk_k<<<NH*LCOMP*HD/256, 256, 0, stream>>>(kf, wk, kchi, kclo);
    poolv_k<<<NH*LCOMP*HD/256, 256, 0, stream>>>(vf, wv, vthi, vtlo);
    padzero_k<<<208, 256, 0, stream>>>(kchi, kclo, vthi, vtlo);
    gather_k<<<NH*NKH*HD/256, 256, 0, stream>>>(kf, vf, hh, kchi, kclo, vthi, vtlo);

    // 5. final attention (writes pre-split ao into x slot)
    attn_mfma<<<dim3(NH, SEQ/16), 256, 0, stream>>>(qsphi, qsplo, kchi, kclo, vthi, vtlo, aohi, aolo);

    // 6. output projection (LDS-staged)
    gemm_lds<64, 64, 0><<<dim3(32, 16), 256, 0, stream>>>(
        aohi, aolo, wohi, wolo, nullptr, nullptr, nullptr, nullptr, nullptr, nullptr, out);
}